// Round 1
// baseline (7460.048 us; speedup 1.0000x reference)
//
#include <hip/hip_runtime.h>
#include <hip/hip_bf16.h>
#include <cstddef>

// ---------------- problem constants ----------------
constexpr int Bb  = 8;
constexpr int Ll  = 2048;
constexpr int OBSn = 64;
constexpr int ACTn = 16;
constexpr int DMn = 768;
constexpr int DIn = 1536;          // d_inner
constexpr int Nn  = 16;            // d_state
constexpr int Rn  = 48;            // dt_rank
constexpr int Kc  = 4;             // d_conv
constexpr int NLn = 2;
constexpr int EO  = 2 * DIn;       // 3072 (xz row width)
constexpr int XD  = Rn + 2 * Nn;   // 80  (x_dbl row width)
constexpr int CH  = 128;           // scan chunk length
constexpr int NCH = Ll / CH;       // 16 chunks

// ---------------- generic f32 GEMM: C[m,n] = act(bias[n] + sum_k A[m,k]*W[n,k]) ----------------
// A: [M,K] row-major with leading dim lda; W: [N,K] row-major with ldw; C: [M,N] ldc.
template<int BM, int BN, int BK, int TM, int TN, int ACT>
__global__ __launch_bounds__((BM / TM) * (BN / TN))
void gemm_nt(const float* __restrict__ A, int lda,
             const float* __restrict__ W, int ldw,
             const float* __restrict__ bias,
             float* __restrict__ C, int ldc,
             int M, int N, int K)
{
    constexpr int NT  = (BM / TM) * (BN / TN);
    constexpr int PAD = 4;
    __shared__ float As[BK][BM + PAD];
    __shared__ float Ws[BK][BN + PAD];

    const int tid  = threadIdx.x;
    constexpr int TNT = BN / TN;           // threads along n
    const int tn   = tid % TNT;
    const int tm   = tid / TNT;
    const int row0 = blockIdx.y * BM;
    const int col0 = blockIdx.x * BN;
    const bool fullM = (row0 + BM <= M);
    const bool fullN = (col0 + BN <= N);

    float acc[TM][TN];
#pragma unroll
    for (int i = 0; i < TM; ++i)
#pragma unroll
        for (int j = 0; j < TN; ++j) acc[i][j] = 0.f;

    for (int k0 = 0; k0 < K; k0 += BK) {
        const bool fullK = (k0 + BK <= K);
        // ---- load A tile ----
        if (fullK && fullM) {
            constexpr int KV  = BK / 4;
            constexpr int ITA = (BM * KV) / NT;
#pragma unroll
            for (int i = 0; i < ITA; ++i) {
                int v = tid + i * NT;
                int m = v / KV, kv = v % KV;
                const float4 f = *reinterpret_cast<const float4*>(
                    A + (size_t)(row0 + m) * lda + k0 + kv * 4);
                As[kv * 4 + 0][m] = f.x; As[kv * 4 + 1][m] = f.y;
                As[kv * 4 + 2][m] = f.z; As[kv * 4 + 3][m] = f.w;
            }
        } else {
            constexpr int ITA = (BM * BK) / NT;
#pragma unroll
            for (int i = 0; i < ITA; ++i) {
                int v = tid + i * NT;
                int m = v / BK, k = v % BK;
                int r = row0 + m, kk = k0 + k;
                float val = 0.f;
                if (r < M && kk < K) val = A[(size_t)r * lda + kk];
                As[k][m] = val;
            }
        }
        // ---- load W tile ----
        if (fullK && fullN) {
            constexpr int KV  = BK / 4;
            constexpr int ITW = (BN * KV) / NT;
#pragma unroll
            for (int i = 0; i < ITW; ++i) {
                int v = tid + i * NT;
                int nn = v / KV, kv = v % KV;
                const float4 f = *reinterpret_cast<const float4*>(
                    W + (size_t)(col0 + nn) * ldw + k0 + kv * 4);
                Ws[kv * 4 + 0][nn] = f.x; Ws[kv * 4 + 1][nn] = f.y;
                Ws[kv * 4 + 2][nn] = f.z; Ws[kv * 4 + 3][nn] = f.w;
            }
        } else {
            constexpr int ITW = (BN * BK) / NT;
#pragma unroll
            for (int i = 0; i < ITW; ++i) {
                int v = tid + i * NT;
                int nn = v / BK, k = v % BK;
                int cc = col0 + nn, kk = k0 + k;
                float val = 0.f;
                if (cc < N && kk < K) val = W[(size_t)cc * ldw + kk];
                Ws[k][nn] = val;
            }
        }
        __syncthreads();
#pragma unroll
        for (int k = 0; k < BK; ++k) {
            float a[TM], bb[TN];
#pragma unroll
            for (int i = 0; i < TM; ++i) a[i] = As[k][tm * TM + i];
#pragma unroll
            for (int j = 0; j < TN; ++j) bb[j] = Ws[k][tn * TN + j];
#pragma unroll
            for (int i = 0; i < TM; ++i)
#pragma unroll
                for (int j = 0; j < TN; ++j) acc[i][j] = fmaf(a[i], bb[j], acc[i][j]);
        }
        __syncthreads();
    }
    // ---- epilogue ----
#pragma unroll
    for (int i = 0; i < TM; ++i) {
        int r = row0 + tm * TM + i;
        if (r >= M) continue;
#pragma unroll
        for (int j = 0; j < TN; ++j) {
            int c = col0 + tn * TN + j;
            if (c >= N) continue;
            float v = acc[i][j];
            if (bias) v += bias[c];
            if constexpr (ACT == 1) v = (v > 20.f) ? v : log1pf(__expf(v));  // softplus
            C[(size_t)r * ldc + c] = v;
        }
    }
}

// ---------------- depthwise causal conv (K=4) + bias + SiLU ----------------
// reads the xa half of xz ([rows, EO], columns [0,DI)), writes xa_c [rows, DI]
__global__ __launch_bounds__(256)
void conv_silu(const float* __restrict__ xz, const float* __restrict__ cw,
               const float* __restrict__ cb, float* __restrict__ xa, int rowsTotal)
{
    int idx = blockIdx.x * blockDim.x + threadIdx.x;
    int total = rowsTotal * DIn;
    if (idx >= total) return;
    int d = idx % DIn;
    int row = idx / DIn;
    int l = row % Ll;
    float acc = cb[d];
#pragma unroll
    for (int j = 0; j < Kc; ++j) {
        int lo = l - (Kc - 1) + j;
        if (lo >= 0)
            acc = fmaf(cw[d * Kc + j], xz[(size_t)(row - (Kc - 1) + j) * EO + d], acc);
    }
    float s = acc / (1.f + __expf(-acc));   // SiLU
    xa[(size_t)row * DIn + d] = s;
}

// ---------------- selective scan, chunked (3 passes) ----------------
// pass 1: per (b,d,chunk): local scan with h0=0 -> h_end, decay product P
__global__ __launch_bounds__(256)
void scan_pass1(const float* __restrict__ dt, const float* __restrict__ xa,
                const float* __restrict__ xdbl, const float* __restrict__ A_log,
                float* __restrict__ hend, float* __restrict__ Pbuf, int BC)
{
    int idx = blockIdx.x * blockDim.x + threadIdx.x;
    int total = BC * DIn * NCH;
    if (idx >= total) return;
    int d = idx % DIn;
    int t = idx / DIn;          // t = b*NCH + c
    int c = t % NCH;
    int b = t / NCH;

    float A[Nn];
#pragma unroll
    for (int n = 0; n < Nn; ++n) A[n] = -__expf(A_log[d * Nn + n]);
    float h[Nn], P[Nn];
#pragma unroll
    for (int n = 0; n < Nn; ++n) { h[n] = 0.f; P[n] = 1.f; }

    int l0 = c * CH;
    for (int l = l0; l < l0 + CH; ++l) {
        size_t row = (size_t)b * Ll + l;
        float dtv = dt[row * DIn + d];
        float xv  = xa[row * DIn + d];
        float cx  = dtv * xv;
        const float* bvec = xdbl + row * XD + Rn;        // B at cols [48,64)
#pragma unroll
        for (int n = 0; n < Nn; ++n) {
            float dA = __expf(dtv * A[n]);
            h[n] = fmaf(dA, h[n], cx * bvec[n]);
            P[n] *= dA;
        }
    }
    float* he = hend + (size_t)idx * Nn;
    float* pp = Pbuf + (size_t)idx * Nn;
#pragma unroll
    for (int n = 0; n < Nn; ++n) { he[n] = h[n]; pp[n] = P[n]; }
}

// pass 2: per (b,d,n): sequential combine over chunks -> h_start per chunk
__global__ __launch_bounds__(256)
void scan_pass2(const float* __restrict__ hend, const float* __restrict__ Pbuf,
                float* __restrict__ hstart, int BC)
{
    int idx = blockIdx.x * blockDim.x + threadIdx.x;
    int total = BC * DIn * Nn;
    if (idx >= total) return;
    int n = idx % Nn;
    int d = (idx / Nn) % DIn;
    int b = idx / (Nn * DIn);
    float hs = 0.f;
    for (int c = 0; c < NCH; ++c) {
        size_t o = (((size_t)b * NCH + c) * DIn + d) * Nn + n;
        hstart[o] = hs;
        hs = fmaf(Pbuf[o], hs, hend[o]);
    }
}

// pass 3: re-scan from h_start, y = h.C + x*D, gate with SiLU(z), write over xa
__global__ __launch_bounds__(256)
void scan_pass3(const float* __restrict__ dt, float* __restrict__ xa,
                const float* __restrict__ xdbl, const float* __restrict__ A_log,
                const float* __restrict__ Dp, const float* __restrict__ xz,
                const float* __restrict__ hstart, int BC)
{
    int idx = blockIdx.x * blockDim.x + threadIdx.x;
    int total = BC * DIn * NCH;
    if (idx >= total) return;
    int d = idx % DIn;
    int t = idx / DIn;
    int c = t % NCH;
    int b = t / NCH;

    float A[Nn];
#pragma unroll
    for (int n = 0; n < Nn; ++n) A[n] = -__expf(A_log[d * Nn + n]);
    float h[Nn];
    const float* hs = hstart + (size_t)idx * Nn;
#pragma unroll
    for (int n = 0; n < Nn; ++n) h[n] = hs[n];
    float Dd = Dp[d];

    int l0 = c * CH;
    for (int l = l0; l < l0 + CH; ++l) {
        size_t row = (size_t)b * Ll + l;
        float dtv = dt[row * DIn + d];
        float xv  = xa[row * DIn + d];
        float cx  = dtv * xv;
        const float* bvec = xdbl + row * XD + Rn;
        const float* cvec = xdbl + row * XD + Rn + Nn;
        float y = 0.f;
#pragma unroll
        for (int n = 0; n < Nn; ++n) {
            float dA = __expf(dtv * A[n]);
            h[n] = fmaf(dA, h[n], cx * bvec[n]);
            y = fmaf(h[n], cvec[n], y);
        }
        y = fmaf(xv, Dd, y);
        float zv = xz[row * EO + DIn + d];
        float sz = zv / (1.f + __expf(-zv));
        xa[row * DIn + d] = y * sz;
    }
}

// ---------------- host launcher ----------------
extern "C" void kernel_launch(void* const* d_in, const int* in_sizes, int n_in,
                              void* d_out, int out_size, void* d_ws, size_t ws_size,
                              hipStream_t stream)
{
    const float* obs        = (const float*)d_in[0];
    const float* w_in       = (const float*)d_in[1];
    const float* b_in       = (const float*)d_in[2];
    const float* in_proj_w  = (const float*)d_in[3];
    const float* conv_w     = (const float*)d_in[4];
    const float* conv_b     = (const float*)d_in[5];
    const float* x_proj_w   = (const float*)d_in[6];
    const float* dt_proj_w  = (const float*)d_in[7];
    const float* dt_proj_b  = (const float*)d_in[8];
    const float* A_log      = (const float*)d_in[9];
    const float* D_skip     = (const float*)d_in[10];
    const float* out_proj_w = (const float*)d_in[11];
    const float* w_out      = (const float*)d_in[12];
    const float* b_out      = (const float*)d_in[13];
    float* out = (float*)d_out;

    const size_t per_b_floats =
        (size_t)Ll * (DMn + 2 * DIn + DIn + XD + DIn) + 3ull * DIn * NCH * Nn;
    int BC = 8;
    while (BC > 1 && per_b_floats * BC * sizeof(float) > ws_size) BC >>= 1;

    const dim3 blk(256);
    for (int b0 = 0; b0 < Bb; b0 += BC) {
        const int rows = BC * Ll;
        float* p = (float*)d_ws;
        float* xbuf = p; p += (size_t)rows * DMn;
        float* xzb  = p; p += (size_t)rows * 2 * DIn;
        float* xab  = p; p += (size_t)rows * DIn;
        float* xdb  = p; p += (size_t)rows * XD;
        float* dtb  = p; p += (size_t)rows * DIn;
        const size_t sseg = (size_t)BC * DIn * NCH * Nn;
        float* hend = p; p += sseg;
        float* Pb   = p; p += sseg;
        float* hst  = p; p += sseg;

        // input projection: x = obs @ w_in^T + b_in
        {
            dim3 g((DMn + 63) / 64, (rows + 127) / 128);
            gemm_nt<128, 64, 32, 8, 4, 0><<<g, blk, 0, stream>>>(
                obs + (size_t)b0 * Ll * OBSn, OBSn, w_in, OBSn, b_in,
                xbuf, DMn, rows, DMn, OBSn);
        }
        for (int layer = 0; layer < NLn; ++layer) {
            const float* ipw    = in_proj_w  + (size_t)layer * 2 * DIn * DMn;
            const float* cw     = conv_w     + (size_t)layer * DIn * Kc;
            const float* cb     = conv_b     + (size_t)layer * DIn;
            const float* xpw    = x_proj_w   + (size_t)layer * XD * DIn;
            const float* dtw    = dt_proj_w  + (size_t)layer * DIn * Rn;
            const float* dtbias = dt_proj_b  + (size_t)layer * DIn;
            const float* Al     = A_log      + (size_t)layer * DIn * Nn;
            const float* Dpp    = D_skip     + (size_t)layer * DIn;
            const float* opw    = out_proj_w + (size_t)layer * DMn * DIn;

            {   // xz = x @ in_proj^T
                dim3 g((2 * DIn + 63) / 64, (rows + 127) / 128);
                gemm_nt<128, 64, 32, 8, 4, 0><<<g, blk, 0, stream>>>(
                    xbuf, DMn, ipw, DMn, nullptr, xzb, 2 * DIn, rows, 2 * DIn, DMn);
            }
            {   // causal depthwise conv + SiLU
                int tot = rows * DIn;
                conv_silu<<<(tot + 255) / 256, blk, 0, stream>>>(xzb, cw, cb, xab, rows);
            }
            {   // x_dbl = xa @ x_proj^T
                dim3 g((XD + 63) / 64, (rows + 127) / 128);
                gemm_nt<128, 64, 32, 8, 4, 0><<<g, blk, 0, stream>>>(
                    xab, DIn, xpw, DIn, nullptr, xdb, XD, rows, XD, DIn);
            }
            {   // dt = softplus(dt_r @ dt_proj^T + dt_b)
                dim3 g((DIn + 63) / 64, (rows + 127) / 128);
                gemm_nt<128, 64, 32, 8, 4, 1><<<g, blk, 0, stream>>>(
                    xdb, XD, dtw, Rn, dtbias, dtb, DIn, rows, DIn, Rn);
            }
            {   // selective scan (chunked) + D skip + SiLU(z) gating
                int tot1 = BC * DIn * NCH;
                scan_pass1<<<(tot1 + 255) / 256, blk, 0, stream>>>(dtb, xab, xdb, Al, hend, Pb, BC);
                int tot2 = BC * DIn * Nn;
                scan_pass2<<<(tot2 + 255) / 256, blk, 0, stream>>>(hend, Pb, hst, BC);
                scan_pass3<<<(tot1 + 255) / 256, blk, 0, stream>>>(dtb, xab, xdb, Al, Dpp, xzb, hst, BC);
            }
            {   // x = y @ out_proj^T
                dim3 g((DMn + 63) / 64, (rows + 127) / 128);
                gemm_nt<128, 64, 32, 8, 4, 0><<<g, blk, 0, stream>>>(
                    xab, DIn, opw, DIn, nullptr, xbuf, DMn, rows, DMn, DIn);
            }
        }
        {   // head: out = x @ w_out^T + b_out
            dim3 g((ACTn + 63) / 64, (rows + 127) / 128);
            gemm_nt<128, 64, 32, 8, 4, 0><<<g, blk, 0, stream>>>(
                xbuf, DMn, w_out, DMn, b_out,
                out + (size_t)b0 * Ll * ACTn, ACTn, rows, ACTn, DMn);
        }
    }
}

// Round 2
// 5050.887 us; speedup vs baseline: 1.4770x; 1.4770x over previous
//
#include <hip/hip_runtime.h>
#include <cstddef>

// ---------------- problem constants ----------------
constexpr int Bb  = 8;
constexpr int Ll  = 2048;
constexpr int OBSn = 64;
constexpr int ACTn = 16;
constexpr int DMn = 768;
constexpr int DIn = 1536;          // d_inner
constexpr int Nn  = 16;            // d_state
constexpr int Rn  = 48;            // dt_rank
constexpr int Kc  = 4;             // d_conv
constexpr int NLn = 2;
constexpr int EO  = 2 * DIn;       // 3072 (xz row width)
constexpr int XD  = Rn + 2 * Nn;   // 80  (x_dbl row width)
constexpr int CH  = 128;           // scan chunk length
constexpr int NCH = Ll / CH;       // 16 chunks
constexpr int KPMAX = 4608;        // max padded K' (3*1536)
constexpr size_t WPMAX = 3072ull * 2304ull;  // max Npad*Kp (in_proj)

typedef __attribute__((ext_vector_type(8))) short short8v;   // 8 bf16 (4 VGPRs)
typedef __attribute__((ext_vector_type(4))) float f32x4;

__device__ inline ushort f2bf(float f) {
    uint u = __float_as_uint(f);
    return (ushort)((u + 0x7FFFu + ((u >> 16) & 1u)) >> 16);   // RNE
}
__device__ inline float bf2f(ushort b) { return __uint_as_float(((uint)b) << 16); }

// ---------------- split-bf16 staging builders ----------------
// A' layout along k': [hi(0:K) | lo(K:2K) | hi(2K:3K) | 0 pad]
__global__ __launch_bounds__(256)
void build_A3(const float* __restrict__ A, int lda, ushort* __restrict__ Ap,
              int M, int K, int Kp)
{
    int kq = Kp >> 2;
    int idx = blockIdx.x * 256 + threadIdx.x;
    if (idx >= M * kq) return;
    int m  = idx / kq;
    int k4 = (idx % kq) << 2;
    ushort4 o;
    if (k4 >= 3 * K) {
        o.x = o.y = o.z = o.w = 0;
    } else {
        int rel = (k4 >= 2 * K) ? k4 - 2 * K : ((k4 >= K) ? k4 - K : k4);
        bool lo = (k4 >= K) && (k4 < 2 * K);
        float4 v = *reinterpret_cast<const float4*>(A + (size_t)m * lda + rel);
        ushort h0 = f2bf(v.x), h1 = f2bf(v.y), h2 = f2bf(v.z), h3 = f2bf(v.w);
        if (lo) {
            h0 = f2bf(v.x - bf2f(h0)); h1 = f2bf(v.y - bf2f(h1));
            h2 = f2bf(v.z - bf2f(h2)); h3 = f2bf(v.w - bf2f(h3));
        }
        o.x = h0; o.y = h1; o.z = h2; o.w = h3;
    }
    *reinterpret_cast<ushort4*>(Ap + (size_t)m * Kp + k4) = o;
}

// W' layout along k': [hi(0:K) | hi(K:2K) | lo(2K:3K) | 0 pad]; rows >= N zeroed
__global__ __launch_bounds__(256)
void build_W3(const float* __restrict__ W, int ldw, ushort* __restrict__ Wp,
              int N, int Npad, int K, int Kp)
{
    int kq = Kp >> 2;
    int idx = blockIdx.x * 256 + threadIdx.x;
    if (idx >= Npad * kq) return;
    int n  = idx / kq;
    int k4 = (idx % kq) << 2;
    ushort4 o;
    if (n >= N || k4 >= 3 * K) {
        o.x = o.y = o.z = o.w = 0;
    } else {
        int rel = (k4 >= 2 * K) ? k4 - 2 * K : ((k4 >= K) ? k4 - K : k4);
        bool lo = (k4 >= 2 * K);
        float4 v = *reinterpret_cast<const float4*>(W + (size_t)n * ldw + rel);
        ushort h0 = f2bf(v.x), h1 = f2bf(v.y), h2 = f2bf(v.z), h3 = f2bf(v.w);
        if (lo) {
            h0 = f2bf(v.x - bf2f(h0)); h1 = f2bf(v.y - bf2f(h1));
            h2 = f2bf(v.z - bf2f(h2)); h3 = f2bf(v.w - bf2f(h3));
        }
        o.x = h0; o.y = h1; o.z = h2; o.w = h3;
    }
    *reinterpret_cast<ushort4*>(Wp + (size_t)n * Kp + k4) = o;
}

// ---------------- bf16 MFMA GEMM: C[m,n] = act(bias[n] + sum_k A'[m,k] W'[n,k]) ----
// 128x128 tile, 4 waves (2x2 of 64x64), BK=32, global_load_lds staging.
__global__ __launch_bounds__(256)
void gemm_bf16(const ushort* __restrict__ Ap, const ushort* __restrict__ Wp,
               const float* __restrict__ bias, float* __restrict__ C, int ldc,
               int M, int N, int Kp, int act)
{
    __shared__ ushort As[128 * 32];
    __shared__ ushort Ws[128 * 32];

    const int tid  = threadIdx.x;
    const int w    = tid >> 6;
    const int lane = tid & 63;
    const int wr   = w >> 1, wc = w & 1;
    const int half = lane >> 4, lid = lane & 15;
    const int row0 = blockIdx.y * 128, col0 = blockIdx.x * 128;

    f32x4 acc[4][4];
#pragma unroll
    for (int i = 0; i < 4; ++i)
#pragma unroll
        for (int j = 0; j < 4; ++j) acc[i][j] = (f32x4){0.f, 0.f, 0.f, 0.f};

    // staging: 8 blocks of 16 rows; block blk covers LDS bytes [blk*1024, +1024)
    // lane l -> row blk*16 + l/4, k-cols (l%4)*8 .. +8  (16B per lane)
    const int r4 = lane >> 2, c8 = (lane & 3) * 8;
    const ushort* gA = Ap + (size_t)(row0 + r4) * Kp + c8;
    const ushort* gW = Wp + (size_t)(col0 + r4) * Kp + c8;

    for (int kt = 0; kt < Kp; kt += 32) {
#pragma unroll
        for (int j = 0; j < 2; ++j) {
            const int blk = w * 2 + j;
            __builtin_amdgcn_global_load_lds(
                (const __attribute__((address_space(1))) uint*)(gA + (size_t)blk * 16 * Kp + kt),
                (__attribute__((address_space(3))) uint*)(&As[blk * 512]), 16, 0, 0);
            __builtin_amdgcn_global_load_lds(
                (const __attribute__((address_space(1))) uint*)(gW + (size_t)blk * 16 * Kp + kt),
                (__attribute__((address_space(3))) uint*)(&Ws[blk * 512]), 16, 0, 0);
        }
        __syncthreads();   // compiler drains vmcnt before barrier

        short8v a[4], b[4];
#pragma unroll
        for (int mi = 0; mi < 4; ++mi)
            a[mi] = *reinterpret_cast<const short8v*>(&As[(wr * 64 + mi * 16 + lid) * 32 + half * 8]);
#pragma unroll
        for (int ni = 0; ni < 4; ++ni)
            b[ni] = *reinterpret_cast<const short8v*>(&Ws[(wc * 64 + ni * 16 + lid) * 32 + half * 8]);
#pragma unroll
        for (int mi = 0; mi < 4; ++mi)
#pragma unroll
            for (int ni = 0; ni < 4; ++ni)
                acc[mi][ni] = __builtin_amdgcn_mfma_f32_16x16x32_bf16(a[mi], b[ni], acc[mi][ni], 0, 0, 0);
        __syncthreads();
    }

    // epilogue: C/D map col=lane&15, row=(lane>>4)*4+q
#pragma unroll
    for (int mi = 0; mi < 4; ++mi) {
        const int r = row0 + wr * 64 + mi * 16 + half * 4;
#pragma unroll
        for (int ni = 0; ni < 4; ++ni) {
            const int c = col0 + wc * 64 + ni * 16 + lid;
            if (c >= N) continue;
            const float bv = bias ? bias[c] : 0.f;
#pragma unroll
            for (int q = 0; q < 4; ++q) {
                float v = acc[mi][ni][q] + bv;
                if (act == 1) v = (v > 20.f) ? v : log1pf(__expf(v));  // softplus
                C[(size_t)(r + q) * ldc + c] = v;
            }
        }
    }
}

// ---------------- depthwise causal conv (K=4) + bias + SiLU ----------------
__global__ __launch_bounds__(256)
void conv_silu(const float* __restrict__ xz, const float* __restrict__ cw,
               const float* __restrict__ cb, float* __restrict__ xa, int rowsTotal)
{
    int idx = blockIdx.x * blockDim.x + threadIdx.x;
    int total = rowsTotal * DIn;
    if (idx >= total) return;
    int d = idx % DIn;
    int row = idx / DIn;
    int l = row % Ll;
    float acc = cb[d];
#pragma unroll
    for (int j = 0; j < Kc; ++j) {
        int lo = l - (Kc - 1) + j;
        if (lo >= 0)
            acc = fmaf(cw[d * Kc + j], xz[(size_t)(row - (Kc - 1) + j) * EO + d], acc);
    }
    float s = acc / (1.f + __expf(-acc));   // SiLU
    xa[(size_t)row * DIn + d] = s;
}

// ---------------- selective scan, chunked (3 passes) ----------------
__global__ __launch_bounds__(256)
void scan_pass1(const float* __restrict__ dt, const float* __restrict__ xa,
                const float* __restrict__ xdbl, const float* __restrict__ A_log,
                float* __restrict__ hend, float* __restrict__ Pbuf, int BC)
{
    int idx = blockIdx.x * blockDim.x + threadIdx.x;
    int total = BC * DIn * NCH;
    if (idx >= total) return;
    int d = idx % DIn;
    int t = idx / DIn;
    int c = t % NCH;
    int b = t / NCH;

    float A[Nn];
#pragma unroll
    for (int n = 0; n < Nn; ++n) A[n] = -__expf(A_log[d * Nn + n]);
    float h[Nn], P[Nn];
#pragma unroll
    for (int n = 0; n < Nn; ++n) { h[n] = 0.f; P[n] = 1.f; }

    int l0 = c * CH;
    for (int l = l0; l < l0 + CH; ++l) {
        size_t row = (size_t)b * Ll + l;
        float dtv = dt[row * DIn + d];
        float xv  = xa[row * DIn + d];
        float cx  = dtv * xv;
        const float* bvec = xdbl + row * XD + Rn;
#pragma unroll
        for (int n = 0; n < Nn; ++n) {
            float dA = __expf(dtv * A[n]);
            h[n] = fmaf(dA, h[n], cx * bvec[n]);
            P[n] *= dA;
        }
    }
    float* he = hend + (size_t)idx * Nn;
    float* pp = Pbuf + (size_t)idx * Nn;
#pragma unroll
    for (int n = 0; n < Nn; ++n) { he[n] = h[n]; pp[n] = P[n]; }
}

__global__ __launch_bounds__(256)
void scan_pass2(const float* __restrict__ hend, const float* __restrict__ Pbuf,
                float* __restrict__ hstart, int BC)
{
    int idx = blockIdx.x * blockDim.x + threadIdx.x;
    int total = BC * DIn * Nn;
    if (idx >= total) return;
    int n = idx % Nn;
    int d = (idx / Nn) % DIn;
    int b = idx / (Nn * DIn);
    float hs = 0.f;
    for (int c = 0; c < NCH; ++c) {
        size_t o = (((size_t)b * NCH + c) * DIn + d) * Nn + n;
        hstart[o] = hs;
        hs = fmaf(Pbuf[o], hs, hend[o]);
    }
}

__global__ __launch_bounds__(256)
void scan_pass3(const float* __restrict__ dt, float* __restrict__ xa,
                const float* __restrict__ xdbl, const float* __restrict__ A_log,
                const float* __restrict__ Dp, const float* __restrict__ xz,
                const float* __restrict__ hstart, int BC)
{
    int idx = blockIdx.x * blockDim.x + threadIdx.x;
    int total = BC * DIn * NCH;
    if (idx >= total) return;
    int d = idx % DIn;
    int t = idx / DIn;
    int c = t % NCH;
    int b = t / NCH;

    float A[Nn];
#pragma unroll
    for (int n = 0; n < Nn; ++n) A[n] = -__expf(A_log[d * Nn + n]);
    float h[Nn];
    const float* hs = hstart + (size_t)idx * Nn;
#pragma unroll
    for (int n = 0; n < Nn; ++n) h[n] = hs[n];
    float Dd = Dp[d];

    int l0 = c * CH;
    for (int l = l0; l < l0 + CH; ++l) {
        size_t row = (size_t)b * Ll + l;
        float dtv = dt[row * DIn + d];
        float xv  = xa[row * DIn + d];
        float cx  = dtv * xv;
        const float* bvec = xdbl + row * XD + Rn;
        const float* cvec = xdbl + row * XD + Rn + Nn;
        float y = 0.f;
#pragma unroll
        for (int n = 0; n < Nn; ++n) {
            float dA = __expf(dtv * A[n]);
            h[n] = fmaf(dA, h[n], cx * bvec[n]);
            y = fmaf(h[n], cvec[n], y);
        }
        y = fmaf(xv, Dd, y);
        float zv = xz[row * EO + DIn + d];
        float sz = zv / (1.f + __expf(-zv));
        xa[row * DIn + d] = y * sz;
    }
}

// ---------------- host-side GEMM helper ----------------
static void run_gemm(const float* A, int lda, int K,
                     const float* W, int ldw, int N,
                     const float* bias, int act,
                     float* C, int ldc, int M,
                     ushort* Abuf, ushort* Wbuf, hipStream_t stream)
{
    const int Kp   = ((3 * K + 31) / 32) * 32;
    const int Npad = ((N + 127) / 128) * 128;
    const int kq   = Kp / 4;
    {
        int tot = M * kq;
        build_A3<<<(tot + 255) / 256, 256, 0, stream>>>(A, lda, Abuf, M, K, Kp);
    }
    {
        int tot = Npad * kq;
        build_W3<<<(tot + 255) / 256, 256, 0, stream>>>(W, ldw, Wbuf, N, Npad, K, Kp);
    }
    dim3 g(Npad / 128, M / 128);
    gemm_bf16<<<g, dim3(256), 0, stream>>>(Abuf, Wbuf, bias, C, ldc, M, N, Kp, act);
}

// ---------------- host launcher ----------------
extern "C" void kernel_launch(void* const* d_in, const int* in_sizes, int n_in,
                              void* d_out, int out_size, void* d_ws, size_t ws_size,
                              hipStream_t stream)
{
    const float* obs        = (const float*)d_in[0];
    const float* w_in       = (const float*)d_in[1];
    const float* b_in       = (const float*)d_in[2];
    const float* in_proj_w  = (const float*)d_in[3];
    const float* conv_w     = (const float*)d_in[4];
    const float* conv_b     = (const float*)d_in[5];
    const float* x_proj_w   = (const float*)d_in[6];
    const float* dt_proj_w  = (const float*)d_in[7];
    const float* dt_proj_b  = (const float*)d_in[8];
    const float* A_log      = (const float*)d_in[9];
    const float* D_skip     = (const float*)d_in[10];
    const float* out_proj_w = (const float*)d_in[11];
    const float* w_out      = (const float*)d_in[12];
    const float* b_out      = (const float*)d_in[13];
    float* out = (float*)d_out;

    auto chunk_bytes = [](int bc) -> size_t {
        size_t rows = (size_t)bc * Ll;
        size_t f32e = rows * (DMn + EO + DIn + XD + DIn) + 3ull * bc * DIn * NCH * Nn;
        size_t bf16e = rows * KPMAX + WPMAX;
        return f32e * 4 + bf16e * 2 + 16 * 12;   // slack for alignment
    };
    int BC = 8;
    while (BC > 1 && chunk_bytes(BC) > ws_size) BC >>= 1;

    const dim3 blk(256);
    for (int b0 = 0; b0 < Bb; b0 += BC) {
        const int rows = BC * Ll;
        char* base = (char*)d_ws;
        auto alloc = [&](size_t bytes) -> char* {
            char* r = base; base += (bytes + 15) & ~(size_t)15; return r;
        };
        float* xbuf = (float*)alloc((size_t)rows * DMn * 4);
        float* xzb  = (float*)alloc((size_t)rows * EO * 4);
        float* xab  = (float*)alloc((size_t)rows * DIn * 4);
        float* xdb  = (float*)alloc((size_t)rows * XD * 4);
        float* dtb  = (float*)alloc((size_t)rows * DIn * 4);
        const size_t sseg = (size_t)BC * DIn * NCH * Nn;
        float* hend = (float*)alloc(sseg * 4);
        float* Pb   = (float*)alloc(sseg * 4);
        float* hst  = (float*)alloc(sseg * 4);
        ushort* Abuf = (ushort*)alloc((size_t)rows * KPMAX * 2);
        ushort* Wbuf = (ushort*)alloc(WPMAX * 2);

        // input projection: x = obs @ w_in^T + b_in
        run_gemm(obs + (size_t)b0 * Ll * OBSn, OBSn, OBSn, w_in, OBSn, DMn,
                 b_in, 0, xbuf, DMn, rows, Abuf, Wbuf, stream);

        for (int layer = 0; layer < NLn; ++layer) {
            const float* ipw    = in_proj_w  + (size_t)layer * EO * DMn;
            const float* cw     = conv_w     + (size_t)layer * DIn * Kc;
            const float* cb     = conv_b     + (size_t)layer * DIn;
            const float* xpw    = x_proj_w   + (size_t)layer * XD * DIn;
            const float* dtw    = dt_proj_w  + (size_t)layer * DIn * Rn;
            const float* dtbias = dt_proj_b  + (size_t)layer * DIn;
            const float* Al     = A_log      + (size_t)layer * DIn * Nn;
            const float* Dpp    = D_skip     + (size_t)layer * DIn;
            const float* opw    = out_proj_w + (size_t)layer * DMn * DIn;

            // xz = x @ in_proj^T
            run_gemm(xbuf, DMn, DMn, ipw, DMn, EO, nullptr, 0,
                     xzb, EO, rows, Abuf, Wbuf, stream);
            // causal depthwise conv + SiLU
            {
                int tot = rows * DIn;
                conv_silu<<<(tot + 255) / 256, blk, 0, stream>>>(xzb, cw, cb, xab, rows);
            }
            // x_dbl = xa @ x_proj^T
            run_gemm(xab, DIn, DIn, xpw, DIn, XD, nullptr, 0,
                     xdb, XD, rows, Abuf, Wbuf, stream);
            // dt = softplus(dt_r @ dt_proj^T + dt_b)
            run_gemm(xdb, XD, Rn, dtw, Rn, DIn, dtbias, 1,
                     dtb, DIn, rows, Abuf, Wbuf, stream);
            // selective scan
            {
                int tot1 = BC * DIn * NCH;
                scan_pass1<<<(tot1 + 255) / 256, blk, 0, stream>>>(dtb, xab, xdb, Al, hend, Pb, BC);
                int tot2 = BC * DIn * Nn;
                scan_pass2<<<(tot2 + 255) / 256, blk, 0, stream>>>(hend, Pb, hst, BC);
                scan_pass3<<<(tot1 + 255) / 256, blk, 0, stream>>>(dtb, xab, xdb, Al, Dpp, xzb, hst, BC);
            }
            // x = y @ out_proj^T
            run_gemm(xab, DIn, DIn, opw, DIn, DMn, nullptr, 0,
                     xbuf, DMn, rows, Abuf, Wbuf, stream);
        }
        // head: out = x @ w_out^T + b_out
        run_gemm(xbuf, DMn, DMn, w_out, DMn, ACTn, b_out, 0,
                 out + (size_t)b0 * Ll * ACTn, ACTn, rows, Abuf, Wbuf, stream);
    }
}

// Round 3
// 2034.582 us; speedup vs baseline: 3.6666x; 2.4825x over previous
//
#include <hip/hip_runtime.h>
#include <cstddef>

// ---------------- problem constants ----------------
constexpr int Bb  = 8;
constexpr int Ll  = 2048;
constexpr int OBSn = 64;
constexpr int ACTn = 16;
constexpr int DMn = 768;
constexpr int DIn = 1536;
constexpr int Nn  = 16;
constexpr int Rn  = 48;
constexpr int Kc  = 4;
constexpr int NLn = 2;
constexpr int XD  = Rn + 2 * Nn;   // 80
constexpr int CH  = 128;
constexpr int NCH = Ll / CH;       // 16

typedef __attribute__((ext_vector_type(8))) short short8v;
typedef __attribute__((ext_vector_type(4))) float f32x4;

__device__ inline ushort f2bf(float f) {
    uint u = __float_as_uint(f);
    return (ushort)((u + 0x7FFFu + ((u >> 16) & 1u)) >> 16);   // RNE
}
__device__ inline float bf2f(ushort b) { return __uint_as_float(((uint)b) << 16); }

// ---------------- W' builder: all weights -> [Whi | Wlo] bf16, once ----------------
// segments: w_in, in_proj x2, x_proj x2, dt_proj x2, out_proj x2, w_out
constexpr size_t WOFF_WIN = 0, WOFF_INP0 = 98304, WOFF_INP1 = 4816896,
                 WOFF_XP0 = 9535488, WOFF_XP1 = 9928704, WOFF_DT0 = 10321920,
                 WOFF_DT1 = 10518528, WOFF_OP0 = 10715136, WOFF_OP1 = 13074432,
                 WOFF_WOUT = 15433728, WTOT = 15630336;   // ushorts
constexpr size_t WQUADS = WTOT / 4;                        // 3,907,584

__global__ __launch_bounds__(256)
void build_wsplit(const float* __restrict__ w_in, const float* __restrict__ inp,
                  const float* __restrict__ xp,  const float* __restrict__ dtp,
                  const float* __restrict__ op,  const float* __restrict__ wout,
                  ushort* __restrict__ WB)
{
    constexpr int NS = 10;
    constexpr int    sSel[NS] = {0,1,1,2,2,3,3,4,4,5};
    constexpr size_t sOff[NS] = {0, 0, 3072ull*768, 0, 80ull*1536, 0, 1536ull*48, 0, 768ull*1536, 0};
    constexpr int    sN[NS]   = {768,3072,3072,80,80,1536,1536,768,768,16};
    constexpr int    sK[NS]   = {64,768,768,1536,1536,48,48,1536,1536,768};
    constexpr int    sKp[NS]  = {64,768,768,1536,1536,64,64,1536,1536,768};
    constexpr size_t sD[NS]   = {WOFF_WIN,WOFF_INP0,WOFF_INP1,WOFF_XP0,WOFF_XP1,
                                 WOFF_DT0,WOFF_DT1,WOFF_OP0,WOFF_OP1,WOFF_WOUT};
    constexpr size_t sQ[NS+1] = {0,24576,1204224,2383872,2482176,2580480,
                                 2629632,2678784,3268608,3858432,3907584};

    size_t qid = (size_t)blockIdx.x * 256 + threadIdx.x;
    if (qid >= sQ[NS]) return;
    int s = 0;
#pragma unroll
    for (int i = 0; i < NS; ++i) if (qid >= sQ[i+1]) s = i + 1;

    size_t local = qid - sQ[s];
    const int Kp = sKp[s], K = sK[s], N = sN[s];
    const int ncol4 = (2 * Kp) >> 2;
    const int n  = (int)(local / ncol4);
    const int c4 = (int)(local % ncol4) * 4;
    const bool lo = (c4 >= Kp);
    const int sc = lo ? c4 - Kp : c4;
    ushort4 o; o.x = o.y = o.z = o.w = 0;
    if (n < N && sc < K) {
        const float* src;
        switch (sSel[s]) { case 0: src = w_in; break; case 1: src = inp; break;
                           case 2: src = xp;   break; case 3: src = dtp; break;
                           case 4: src = op;   break; default: src = wout; }
        float4 v = *reinterpret_cast<const float4*>(src + sOff[s] + (size_t)n * K + sc);
        ushort h0 = f2bf(v.x), h1 = f2bf(v.y), h2 = f2bf(v.z), h3 = f2bf(v.w);
        if (lo) {
            h0 = f2bf(v.x - bf2f(h0)); h1 = f2bf(v.y - bf2f(h1));
            h2 = f2bf(v.z - bf2f(h2)); h3 = f2bf(v.w - bf2f(h3));
        }
        o.x = h0; o.y = h1; o.z = h2; o.w = h3;
    }
    *reinterpret_cast<ushort4*>(WB + sD[s] + (size_t)n * (2 * Kp) + c4) = o;
}

// ---------------- plain f32 -> bf16 converter (obs) ----------------
__global__ __launch_bounds__(256)
void build_bf(const float* __restrict__ src, ushort* __restrict__ dst, int n4)
{
    int i = blockIdx.x * 256 + threadIdx.x;
    if (i >= n4) return;
    float4 v = *reinterpret_cast<const float4*>(src + (size_t)i * 4);
    ushort4 o; o.x = f2bf(v.x); o.y = f2bf(v.y); o.z = f2bf(v.z); o.w = f2bf(v.w);
    *reinterpret_cast<ushort4*>(dst + (size_t)i * 4) = o;
}

// ---------------- MFMA GEMM (A bf16 [MxKp], W' [Npad x 2Kp]) ----------------
// BM in {128, 64}; BN=128; 4 waves (2x2). OUT: 0=f32, 1=bf16, 2=softplus f32,
// 3=xz-mix (c<DIn -> f32 Cf, else bf16 Cb). SPLITK: write raw partials.
template<int BM, int OUT, int SPLITK>
__global__ __launch_bounds__(256)
void gemm_ws(const ushort* __restrict__ Ap, int lda,
             const ushort* __restrict__ Wp,
             const float* __restrict__ bias,
             float* __restrict__ Cf, ushort* __restrict__ Cb, int ldc,
             int M, int N, int Kp, int ktLen)
{
    constexpr int MI = BM / 32;           // acc rows of 16
    __shared__ ushort As[BM * 32];
    __shared__ ushort Ws2[8192];          // hi: [0,4096), lo: [4096,8192)

    const int nwgx = gridDim.x;
    const int nwg  = nwgx * gridDim.y;
    int bid = blockIdx.y * nwgx + blockIdx.x;
    {   // bijective XCD swizzle
        int q = nwg >> 3, r = nwg & 7;
        int x = bid & 7, lc = bid >> 3;
        bid = (x < r ? x * (q + 1) : r * (q + 1) + (x - r) * q) + lc;
    }
    const int col0 = (bid % nwgx) * 128;
    const int row0 = (bid / nwgx) * BM;

    const int tid = threadIdx.x, w = tid >> 6, lane = tid & 63;
    const int wr = w >> 1, wc = w & 1, half = lane >> 4, lid = lane & 15;

    f32x4 acc[MI][4];
#pragma unroll
    for (int i = 0; i < MI; ++i)
#pragma unroll
        for (int j = 0; j < 4; ++j) acc[i][j] = (f32x4){0.f, 0.f, 0.f, 0.f};

    const int gr = lane >> 2, gc8 = (lane & 3) * 8;
    const int ldw = 2 * Kp;
    const int kt0 = SPLITK ? blockIdx.z * ktLen : 0;

    for (int kt = kt0; kt < kt0 + ktLen; kt += 32) {
        if constexpr (BM == 128) {
#pragma unroll
            for (int j = 0; j < 2; ++j) {
                int g = w * 2 + j;
                __builtin_amdgcn_global_load_lds(
                    (const __attribute__((address_space(1))) uint*)(Ap + (size_t)(row0 + g*16 + gr) * lda + kt + gc8),
                    (__attribute__((address_space(3))) uint*)(&As[g * 512]), 16, 0, 0);
            }
        } else {
            int g = w;
            __builtin_amdgcn_global_load_lds(
                (const __attribute__((address_space(1))) uint*)(Ap + (size_t)(row0 + g*16 + gr) * lda + kt + gc8),
                (__attribute__((address_space(3))) uint*)(&As[g * 512]), 16, 0, 0);
        }
#pragma unroll
        for (int j = 0; j < 2; ++j) {
            int g = w * 2 + j;
            const ushort* wsrc = Wp + (size_t)(col0 + g*16 + gr) * ldw + kt + gc8;
            __builtin_amdgcn_global_load_lds(
                (const __attribute__((address_space(1))) uint*)wsrc,
                (__attribute__((address_space(3))) uint*)(&Ws2[g * 512]), 16, 0, 0);
            __builtin_amdgcn_global_load_lds(
                (const __attribute__((address_space(1))) uint*)(wsrc + Kp),
                (__attribute__((address_space(3))) uint*)(&Ws2[4096 + g * 512]), 16, 0, 0);
        }
        __syncthreads();

        short8v a[MI], bh[4], bl[4];
#pragma unroll
        for (int mi = 0; mi < MI; ++mi)
            a[mi] = *reinterpret_cast<const short8v*>(&As[(wr*(BM/2) + mi*16 + lid) * 32 + half * 8]);
#pragma unroll
        for (int ni = 0; ni < 4; ++ni) {
            bh[ni] = *reinterpret_cast<const short8v*>(&Ws2[(wc*64 + ni*16 + lid) * 32 + half * 8]);
            bl[ni] = *reinterpret_cast<const short8v*>(&Ws2[4096 + (wc*64 + ni*16 + lid) * 32 + half * 8]);
        }
#pragma unroll
        for (int mi = 0; mi < MI; ++mi)
#pragma unroll
            for (int ni = 0; ni < 4; ++ni)
                acc[mi][ni] = __builtin_amdgcn_mfma_f32_16x16x32_bf16(a[mi], bh[ni], acc[mi][ni], 0, 0, 0);
#pragma unroll
        for (int mi = 0; mi < MI; ++mi)
#pragma unroll
            for (int ni = 0; ni < 4; ++ni)
                acc[mi][ni] = __builtin_amdgcn_mfma_f32_16x16x32_bf16(a[mi], bl[ni], acc[mi][ni], 0, 0, 0);
        __syncthreads();
    }

    if constexpr (SPLITK) {
        float* P = Cf + (size_t)blockIdx.z * M * 128;
#pragma unroll
        for (int mi = 0; mi < MI; ++mi) {
            int r = row0 + wr*(BM/2) + mi*16 + half*4;
#pragma unroll
            for (int ni = 0; ni < 4; ++ni) {
                int c = col0 + wc*64 + ni*16 + lid;   // grid.x==1 -> col0==0
#pragma unroll
                for (int q = 0; q < 4; ++q)
                    P[(size_t)(r + q) * 128 + c] = acc[mi][ni][q];
            }
        }
    } else if constexpr (OUT == 3) {
#pragma unroll
        for (int mi = 0; mi < MI; ++mi) {
            int r = row0 + wr*(BM/2) + mi*16 + half*4;
#pragma unroll
            for (int ni = 0; ni < 4; ++ni) {
                int c = col0 + wc*64 + ni*16 + lid;
                if (c < DIn) {
#pragma unroll
                    for (int q = 0; q < 4; ++q) Cf[(size_t)(r + q) * DIn + c] = acc[mi][ni][q];
                } else {
#pragma unroll
                    for (int q = 0; q < 4; ++q) Cb[(size_t)(r + q) * DIn + (c - DIn)] = f2bf(acc[mi][ni][q]);
                }
            }
        }
    } else {
#pragma unroll
        for (int mi = 0; mi < MI; ++mi) {
            int r = row0 + wr*(BM/2) + mi*16 + half*4;
#pragma unroll
            for (int ni = 0; ni < 4; ++ni) {
                int c = col0 + wc*64 + ni*16 + lid;
                if (c >= N) continue;
                float bv = bias ? bias[c] : 0.f;
#pragma unroll
                for (int q = 0; q < 4; ++q) {
                    float v = acc[mi][ni][q] + bv;
                    if constexpr (OUT == 2) v = (v > 20.f) ? v : log1pf(__expf(v));
                    if constexpr (OUT == 1) Cb[(size_t)(r + q) * ldc + c] = f2bf(v);
                    else                    Cf[(size_t)(r + q) * ldc + c] = v;
                }
            }
        }
    }
}

// ---------------- split-K reduce (+bias/+bf16 mirror with zero pad) ----------------
__global__ __launch_bounds__(256)
void reduce_sk(const float* __restrict__ P, int S, int M,
               const float* __restrict__ bias,
               float* __restrict__ Cf, int ldc, int N,
               ushort* __restrict__ Cb, int nbf, int nbfPad)
{
    int idx = blockIdx.x * 256 + threadIdx.x;
    if (idx >= M * 128) return;
    int c = idx & 127, r = idx >> 7;
    float v = 0.f;
    for (int s = 0; s < S; ++s) v += P[(size_t)s * M * 128 + idx];
    if (bias) v += bias[c];
    if (c < N) Cf[(size_t)r * ldc + c] = v;
    if (Cb && c < nbfPad) Cb[(size_t)r * nbfPad + c] = (c < nbf) ? f2bf(v) : (ushort)0;
}

// ---------------- depthwise causal conv (K=4) + bias + SiLU -> bf16 ----------------
__global__ __launch_bounds__(256)
void conv_silu(const float* __restrict__ xa, const float* __restrict__ cw,
               const float* __restrict__ cb, ushort* __restrict__ xo, int rowsTotal)
{
    int idx = blockIdx.x * 256 + threadIdx.x;
    if (idx >= rowsTotal * DIn) return;
    int d = idx % DIn, row = idx / DIn, l = row % Ll;
    float acc = cb[d];
#pragma unroll
    for (int j = 0; j < Kc; ++j) {
        int lo = l - 3 + j;
        if (lo >= 0) acc = fmaf(cw[d * Kc + j], xa[(size_t)(row - 3 + j) * DIn + d], acc);
    }
    float s = acc / (1.f + __expf(-acc));
    xo[(size_t)row * DIn + d] = f2bf(s);
}

// ---------------- selective scan, chunked ----------------
__global__ __launch_bounds__(256)
void scan_pass1(const float* __restrict__ dt, const ushort* __restrict__ xab,
                const float* __restrict__ xdbl, const float* __restrict__ A_log,
                float* __restrict__ hend, float* __restrict__ Pbuf, int BC)
{
    int idx = blockIdx.x * 256 + threadIdx.x;
    if (idx >= BC * DIn * NCH) return;
    int d = idx % DIn;
    int t = idx / DIn;
    int c = t % NCH, b = t / NCH;

    float A[Nn];
#pragma unroll
    for (int n = 0; n < Nn; ++n) A[n] = -__expf(A_log[d * Nn + n]);
    float h[Nn], P[Nn];
#pragma unroll
    for (int n = 0; n < Nn; ++n) { h[n] = 0.f; P[n] = 1.f; }

    int l0 = c * CH;
    for (int l = l0; l < l0 + CH; ++l) {
        size_t row = (size_t)b * Ll + l;
        float dtv = dt[row * DIn + d];
        float xv  = bf2f(xab[row * DIn + d]);
        float cx  = dtv * xv;
        const float* bvec = xdbl + row * XD + Rn;
#pragma unroll
        for (int n = 0; n < Nn; ++n) {
            float dA = __expf(dtv * A[n]);
            h[n] = fmaf(dA, h[n], cx * bvec[n]);
            P[n] *= dA;
        }
    }
    float* he = hend + (size_t)idx * Nn;
    float* pp = Pbuf + (size_t)idx * Nn;
#pragma unroll
    for (int n = 0; n < Nn; ++n) { he[n] = h[n]; pp[n] = P[n]; }
}

__global__ __launch_bounds__(256)
void scan_pass2(const float* __restrict__ hend, const float* __restrict__ Pbuf,
                float* __restrict__ hstart, int BC)
{
    int idx = blockIdx.x * 256 + threadIdx.x;
    if (idx >= BC * DIn * Nn) return;
    int n = idx % Nn;
    int d = (idx / Nn) % DIn;
    int b = idx / (Nn * DIn);
    float hs = 0.f;
    for (int c = 0; c < NCH; ++c) {
        size_t o = (((size_t)b * NCH + c) * DIn + d) * Nn + n;
        hstart[o] = hs;
        hs = fmaf(Pbuf[o], hs, hend[o]);
    }
}

__global__ __launch_bounds__(256)
void scan_pass3(const float* __restrict__ dt, ushort* __restrict__ xab,
                const float* __restrict__ xdbl, const float* __restrict__ A_log,
                const float* __restrict__ Dp, const ushort* __restrict__ zb,
                const float* __restrict__ hstart, int BC)
{
    int idx = blockIdx.x * 256 + threadIdx.x;
    if (idx >= BC * DIn * NCH) return;
    int d = idx % DIn;
    int t = idx / DIn;
    int c = t % NCH, b = t / NCH;

    float A[Nn];
#pragma unroll
    for (int n = 0; n < Nn; ++n) A[n] = -__expf(A_log[d * Nn + n]);
    float h[Nn];
    const float* hs = hstart + (size_t)idx * Nn;
#pragma unroll
    for (int n = 0; n < Nn; ++n) h[n] = hs[n];
    float Dd = Dp[d];

    int l0 = c * CH;
    for (int l = l0; l < l0 + CH; ++l) {
        size_t row = (size_t)b * Ll + l;
        float dtv = dt[row * DIn + d];
        float xv  = bf2f(xab[row * DIn + d]);
        float cx  = dtv * xv;
        const float* bvec = xdbl + row * XD + Rn;
        const float* cvec = xdbl + row * XD + Rn + Nn;
        float y = 0.f;
#pragma unroll
        for (int n = 0; n < Nn; ++n) {
            float dA = __expf(dtv * A[n]);
            h[n] = fmaf(dA, h[n], cx * bvec[n]);
            y = fmaf(h[n], cvec[n], y);
        }
        y = fmaf(xv, Dd, y);
        float zv = bf2f(zb[row * DIn + d]);
        float sz = zv / (1.f + __expf(-zv));
        xab[row * DIn + d] = f2bf(y * sz);
    }
}

// ---------------- host launcher ----------------
extern "C" void kernel_launch(void* const* d_in, const int* in_sizes, int n_in,
                              void* d_out, int out_size, void* d_ws, size_t ws_size,
                              hipStream_t stream)
{
    const float* obs        = (const float*)d_in[0];
    const float* w_in       = (const float*)d_in[1];
    const float* b_in       = (const float*)d_in[2];
    const float* in_proj_w  = (const float*)d_in[3];
    const float* conv_w     = (const float*)d_in[4];
    const float* conv_b     = (const float*)d_in[5];
    const float* x_proj_w   = (const float*)d_in[6];
    const float* dt_proj_w  = (const float*)d_in[7];
    const float* dt_proj_b  = (const float*)d_in[8];
    const float* A_log      = (const float*)d_in[9];
    const float* D_skip     = (const float*)d_in[10];
    const float* out_proj_w = (const float*)d_in[11];
    const float* w_out      = (const float*)d_in[12];
    const float* b_out      = (const float*)d_in[13];
    float* out = (float*)d_out;

    // per-BC activation bytes
    auto per_bc = []() -> size_t {
        size_t r = Ll;
        size_t bts = r*DIn*4      // xa_f32
                   + r*DIn*2      // z_bf
                   + r*DIn*2      // xab_bf
                   + r*DIn*4      // dtb
                   + r*XD*4       // xdb
                   + r*64*2       // dtr_bf
                   + r*DMn*2      // xbuf_bf
                   + r*OBSn*2     // obs_bf
                   + 3ull*DIn*NCH*Nn*4   // hend/P/hst
                   + 4ull*r*128*4;       // splitK partials
        return bts + 4096;       // align slack
    };
    const size_t wbytes = WTOT * 2 + 1024;
    int BC = 8;
    while (BC > 1 && wbytes + per_bc() * BC > ws_size) BC >>= 1;

    // weights once
    ushort* WB = (ushort*)d_ws;
    build_wsplit<<<(int)((WQUADS + 255) / 256), 256, 0, stream>>>(
        w_in, in_proj_w, x_proj_w, dt_proj_w, out_proj_w, w_out, WB);

    const size_t WLAY_INP[2] = {WOFF_INP0, WOFF_INP1};
    const size_t WLAY_XP[2]  = {WOFF_XP0,  WOFF_XP1};
    const size_t WLAY_DT[2]  = {WOFF_DT0,  WOFF_DT1};
    const size_t WLAY_OP[2]  = {WOFF_OP0,  WOFF_OP1};

    for (int b0 = 0; b0 < Bb; b0 += BC) {
        const int M = BC * Ll;
        char* base = (char*)d_ws + ((wbytes + 255) & ~(size_t)255);
        auto alloc = [&](size_t bytes) -> char* {
            char* r = base; base += (bytes + 255) & ~(size_t)255; return r;
        };
        float*  xa_f  = (float*) alloc((size_t)M * DIn * 4);
        ushort* z_bf  = (ushort*)alloc((size_t)M * DIn * 2);
        ushort* xab   = (ushort*)alloc((size_t)M * DIn * 2);
        float*  dtb   = (float*) alloc((size_t)M * DIn * 4);
        float*  xdb   = (float*) alloc((size_t)M * XD * 4);
        ushort* dtr   = (ushort*)alloc((size_t)M * 64 * 2);
        ushort* xbuf  = (ushort*)alloc((size_t)M * DMn * 2);
        ushort* obsb  = (ushort*)alloc((size_t)M * OBSn * 2);
        const size_t sseg = (size_t)BC * DIn * NCH * Nn;
        float*  hend  = (float*) alloc(sseg * 4);
        float*  Pb    = (float*) alloc(sseg * 4);
        float*  hst   = (float*) alloc(sseg * 4);
        float*  parts = (float*) alloc(4ull * M * 128 * 4);

        // obs -> bf16
        build_bf<<<(M * OBSn / 4 + 255) / 256, 256, 0, stream>>>(
            obs + (size_t)b0 * Ll * OBSn, obsb, M * OBSn / 4);
        // in_proj: x = obs @ w_in^T + b_in  -> bf16 xbuf
        gemm_ws<64, 1, 0><<<dim3(6, M / 64), 256, 0, stream>>>(
            obsb, OBSn, WB + WOFF_WIN, b_in, nullptr, xbuf, DMn, M, DMn, 64, 64);

        for (int layer = 0; layer < NLn; ++layer) {
            const float* cw     = conv_w    + (size_t)layer * DIn * Kc;
            const float* cb     = conv_b    + (size_t)layer * DIn;
            const float* dtbias = dt_proj_b + (size_t)layer * DIn;
            const float* Al     = A_log     + (size_t)layer * DIn * Nn;
            const float* Dpp    = D_skip    + (size_t)layer * DIn;

            // xz: xa-half -> f32, z-half -> bf16
            gemm_ws<128, 3, 0><<<dim3(24, M / 128), 256, 0, stream>>>(
                xbuf, DMn, WB + WLAY_INP[layer], nullptr, xa_f, z_bf, DIn, M, 2*DIn, DMn, DMn);
            // conv + SiLU -> bf16 xab
            conv_silu<<<(M * DIn + 255) / 256, 256, 0, stream>>>(xa_f, cw, cb, xab, M);
            // x_proj: split-K S=4 -> partials -> xdb f32 + dtr bf16 (pad 64)
            gemm_ws<64, 0, 1><<<dim3(1, M / 64, 4), 256, 0, stream>>>(
                xab, DIn, WB + WLAY_XP[layer], nullptr, parts, nullptr, 128, M, 128, DIn, DIn / 4);
            reduce_sk<<<(M * 128 + 255) / 256, 256, 0, stream>>>(
                parts, 4, M, nullptr, xdb, XD, XD, dtr, Rn, 64);
            // dt = softplus(dtr @ dtw^T + b) -> f32
            gemm_ws<64, 2, 0><<<dim3(12, M / 64), 256, 0, stream>>>(
                dtr, 64, WB + WLAY_DT[layer], dtbias, dtb, nullptr, DIn, M, DIn, 64, 64);
            // selective scan (y gated -> bf16, in place over xab)
            {
                int tot1 = BC * DIn * NCH;
                scan_pass1<<<(tot1 + 255) / 256, 256, 0, stream>>>(dtb, xab, xdb, Al, hend, Pb, BC);
                int tot2 = BC * DIn * Nn;
                scan_pass2<<<(tot2 + 255) / 256, 256, 0, stream>>>(hend, Pb, hst, BC);
                scan_pass3<<<(tot1 + 255) / 256, 256, 0, stream>>>(dtb, xab, xdb, Al, Dpp, z_bf, hst, BC);
            }
            // out_proj -> bf16 xbuf
            gemm_ws<64, 1, 0><<<dim3(6, M / 64), 256, 0, stream>>>(
                xab, DIn, WB + WLAY_OP[layer], nullptr, nullptr, xbuf, DMn, M, DMn, DIn, DIn);
        }
        // head: split-K S=4 -> partials -> out f32 (+b_out)
        gemm_ws<64, 0, 1><<<dim3(1, M / 64, 4), 256, 0, stream>>>(
            xbuf, DMn, WB + WOFF_WOUT, nullptr, parts, nullptr, 128, M, 128, DMn, DMn / 4);
        reduce_sk<<<(M * 128 + 255) / 256, 256, 0, stream>>>(
            parts, 4, M, b_out, out + (size_t)b0 * Ll * ACTn, ACTn, ACTn, nullptr, 0, 0);
    }
}

// Round 4
// 1708.025 us; speedup vs baseline: 4.3676x; 1.1912x over previous
//
#include <hip/hip_runtime.h>
#include <cstddef>

// ---------------- problem constants ----------------
constexpr int Bb  = 8;
constexpr int Ll  = 2048;
constexpr int OBSn = 64;
constexpr int ACTn = 16;
constexpr int DMn = 768;
constexpr int DIn = 1536;
constexpr int Nn  = 16;
constexpr int Rn  = 48;
constexpr int Kc  = 4;
constexpr int NLn = 2;
constexpr int XD  = Rn + 2 * Nn;   // 80
constexpr int CH  = 128;
constexpr int NCH = Ll / CH;       // 16
constexpr int EOc = 2 * DIn;       // 3072

typedef __attribute__((ext_vector_type(8))) short short8v;
typedef __attribute__((ext_vector_type(4))) float f32x4;

__device__ inline ushort f2bf(float f) {
    uint u = __float_as_uint(f);
    return (ushort)((u + 0x7FFFu + ((u >> 16) & 1u)) >> 16);   // RNE
}
__device__ inline float bf2f(ushort b) { return __uint_as_float(((uint)b) << 16); }

// ---------------- W' builder: all weights -> [Whi | Wlo] bf16, once ----------------
constexpr size_t WOFF_WIN = 0, WOFF_INP0 = 98304, WOFF_INP1 = 4816896,
                 WOFF_XP0 = 9535488, WOFF_XP1 = 9928704, WOFF_DT0 = 10321920,
                 WOFF_DT1 = 10518528, WOFF_OP0 = 10715136, WOFF_OP1 = 13074432,
                 WOFF_WOUT = 15433728, WTOT = 15630336;   // ushorts
constexpr size_t WQUADS = WTOT / 4;

__global__ __launch_bounds__(256)
void build_wsplit(const float* __restrict__ w_in, const float* __restrict__ inp,
                  const float* __restrict__ xp,  const float* __restrict__ dtp,
                  const float* __restrict__ op,  const float* __restrict__ wout,
                  ushort* __restrict__ WB)
{
    constexpr int NS = 10;
    constexpr int    sSel[NS] = {0,1,1,2,2,3,3,4,4,5};
    constexpr size_t sOff[NS] = {0, 0, 3072ull*768, 0, 80ull*1536, 0, 1536ull*48, 0, 768ull*1536, 0};
    constexpr int    sN[NS]   = {768,3072,3072,80,80,1536,1536,768,768,16};
    constexpr int    sK[NS]   = {64,768,768,1536,1536,48,48,1536,1536,768};
    constexpr int    sKp[NS]  = {64,768,768,1536,1536,64,64,1536,1536,768};
    constexpr size_t sD[NS]   = {WOFF_WIN,WOFF_INP0,WOFF_INP1,WOFF_XP0,WOFF_XP1,
                                 WOFF_DT0,WOFF_DT1,WOFF_OP0,WOFF_OP1,WOFF_WOUT};
    constexpr size_t sQ[NS+1] = {0,24576,1204224,2383872,2482176,2580480,
                                 2629632,2678784,3268608,3858432,3907584};

    size_t qid = (size_t)blockIdx.x * 256 + threadIdx.x;
    if (qid >= sQ[NS]) return;
    int s = 0;
#pragma unroll
    for (int i = 0; i < NS; ++i) if (qid >= sQ[i+1]) s = i + 1;

    size_t local = qid - sQ[s];
    const int Kp = sKp[s], K = sK[s], N = sN[s];
    const int ncol4 = (2 * Kp) >> 2;
    const int n  = (int)(local / ncol4);
    const int c4 = (int)(local % ncol4) * 4;
    const bool lo = (c4 >= Kp);
    const int sc = lo ? c4 - Kp : c4;
    ushort4 o; o.x = o.y = o.z = o.w = 0;
    if (n < N && sc < K) {
        const float* src;
        switch (sSel[s]) { case 0: src = w_in; break; case 1: src = inp; break;
                           case 2: src = xp;   break; case 3: src = dtp; break;
                           case 4: src = op;   break; default: src = wout; }
        float4 v = *reinterpret_cast<const float4*>(src + sOff[s] + (size_t)n * K + sc);
        ushort h0 = f2bf(v.x), h1 = f2bf(v.y), h2 = f2bf(v.z), h3 = f2bf(v.w);
        if (lo) {
            h0 = f2bf(v.x - bf2f(h0)); h1 = f2bf(v.y - bf2f(h1));
            h2 = f2bf(v.z - bf2f(h2)); h3 = f2bf(v.w - bf2f(h3));
        }
        o.x = h0; o.y = h1; o.z = h2; o.w = h3;
    }
    *reinterpret_cast<ushort4*>(WB + sD[s] + (size_t)n * (2 * Kp) + c4) = o;
}

__global__ __launch_bounds__(256)
void build_bf(const float* __restrict__ src, ushort* __restrict__ dst, int n4)
{
    int i = blockIdx.x * 256 + threadIdx.x;
    if (i >= n4) return;
    float4 v = *reinterpret_cast<const float4*>(src + (size_t)i * 4);
    ushort4 o; o.x = f2bf(v.x); o.y = f2bf(v.y); o.z = f2bf(v.z); o.w = f2bf(v.w);
    *reinterpret_cast<ushort4*>(dst + (size_t)i * 4) = o;
}

// ---------------- MFMA GEMM (A bf16 [MxKp], W' [Npad x 2Kp]) ----------------
// OUT: 0=f32, 1=bf16, 2=softplus f32. SPLITK: raw partials.
template<int BM, int OUT, int SPLITK>
__global__ __launch_bounds__(256)
void gemm_ws(const ushort* __restrict__ Ap, int lda,
             const ushort* __restrict__ Wp,
             const float* __restrict__ bias,
             float* __restrict__ Cf, ushort* __restrict__ Cb, int ldc,
             int M, int N, int Kp, int ktLen)
{
    constexpr int MI = BM / 32;
    __shared__ ushort As[BM * 32];
    __shared__ ushort Ws2[8192];

    const int nwgx = gridDim.x;
    const int nwg  = nwgx * gridDim.y;
    int bid = blockIdx.y * nwgx + blockIdx.x;
    {   // bijective XCD swizzle
        int q = nwg >> 3, r = nwg & 7;
        int x = bid & 7, lc = bid >> 3;
        bid = (x < r ? x * (q + 1) : r * (q + 1) + (x - r) * q) + lc;
    }
    const int col0 = (bid % nwgx) * 128;
    const int row0 = (bid / nwgx) * BM;

    const int tid = threadIdx.x, w = tid >> 6, lane = tid & 63;
    const int wr = w >> 1, wc = w & 1, half = lane >> 4, lid = lane & 15;

    f32x4 acc[MI][4];
#pragma unroll
    for (int i = 0; i < MI; ++i)
#pragma unroll
        for (int j = 0; j < 4; ++j) acc[i][j] = (f32x4){0.f, 0.f, 0.f, 0.f};

    const int gr = lane >> 2, gc8 = (lane & 3) * 8;
    const int ldw = 2 * Kp;
    const int kt0 = SPLITK ? blockIdx.z * ktLen : 0;

    for (int kt = kt0; kt < kt0 + ktLen; kt += 32) {
        if constexpr (BM == 128) {
#pragma unroll
            for (int j = 0; j < 2; ++j) {
                int g = w * 2 + j;
                __builtin_amdgcn_global_load_lds(
                    (const __attribute__((address_space(1))) uint*)(Ap + (size_t)(row0 + g*16 + gr) * lda + kt + gc8),
                    (__attribute__((address_space(3))) uint*)(&As[g * 512]), 16, 0, 0);
            }
        } else {
            int g = w;
            __builtin_amdgcn_global_load_lds(
                (const __attribute__((address_space(1))) uint*)(Ap + (size_t)(row0 + g*16 + gr) * lda + kt + gc8),
                (__attribute__((address_space(3))) uint*)(&As[g * 512]), 16, 0, 0);
        }
#pragma unroll
        for (int j = 0; j < 2; ++j) {
            int g = w * 2 + j;
            const ushort* wsrc = Wp + (size_t)(col0 + g*16 + gr) * ldw + kt + gc8;
            __builtin_amdgcn_global_load_lds(
                (const __attribute__((address_space(1))) uint*)wsrc,
                (__attribute__((address_space(3))) uint*)(&Ws2[g * 512]), 16, 0, 0);
            __builtin_amdgcn_global_load_lds(
                (const __attribute__((address_space(1))) uint*)(wsrc + Kp),
                (__attribute__((address_space(3))) uint*)(&Ws2[4096 + g * 512]), 16, 0, 0);
        }
        __syncthreads();

        short8v a[MI], bh[4], bl[4];
#pragma unroll
        for (int mi = 0; mi < MI; ++mi)
            a[mi] = *reinterpret_cast<const short8v*>(&As[(wr*(BM/2) + mi*16 + lid) * 32 + half * 8]);
#pragma unroll
        for (int ni = 0; ni < 4; ++ni) {
            bh[ni] = *reinterpret_cast<const short8v*>(&Ws2[(wc*64 + ni*16 + lid) * 32 + half * 8]);
            bl[ni] = *reinterpret_cast<const short8v*>(&Ws2[4096 + (wc*64 + ni*16 + lid) * 32 + half * 8]);
        }
#pragma unroll
        for (int mi = 0; mi < MI; ++mi)
#pragma unroll
            for (int ni = 0; ni < 4; ++ni)
                acc[mi][ni] = __builtin_amdgcn_mfma_f32_16x16x32_bf16(a[mi], bh[ni], acc[mi][ni], 0, 0, 0);
#pragma unroll
        for (int mi = 0; mi < MI; ++mi)
#pragma unroll
            for (int ni = 0; ni < 4; ++ni)
                acc[mi][ni] = __builtin_amdgcn_mfma_f32_16x16x32_bf16(a[mi], bl[ni], acc[mi][ni], 0, 0, 0);
        __syncthreads();
    }

    if constexpr (SPLITK) {
        float* P = Cf + (size_t)blockIdx.z * M * 128;
#pragma unroll
        for (int mi = 0; mi < MI; ++mi) {
            int r = row0 + wr*(BM/2) + mi*16 + half*4;
#pragma unroll
            for (int ni = 0; ni < 4; ++ni) {
                int c = col0 + wc*64 + ni*16 + lid;
#pragma unroll
                for (int q = 0; q < 4; ++q)
                    P[(size_t)(r + q) * 128 + c] = acc[mi][ni][q];
            }
        }
    } else {
#pragma unroll
        for (int mi = 0; mi < MI; ++mi) {
            int r = row0 + wr*(BM/2) + mi*16 + half*4;
#pragma unroll
            for (int ni = 0; ni < 4; ++ni) {
                int c = col0 + wc*64 + ni*16 + lid;
                if (c >= N) continue;
                float bv = bias ? bias[c] : 0.f;
#pragma unroll
                for (int q = 0; q < 4; ++q) {
                    float v = acc[mi][ni][q] + bv;
                    if constexpr (OUT == 2) v = (v > 20.f) ? v : log1pf(__expf(v));
                    if constexpr (OUT == 1) Cb[(size_t)(r + q) * ldc + c] = f2bf(v);
                    else                    Cf[(size_t)(r + q) * ldc + c] = v;
                }
            }
        }
    }
}

// ---------------- split-K reduce ----------------
__global__ __launch_bounds__(256)
void reduce_sk(const float* __restrict__ P, int S, int M,
               const float* __restrict__ bias,
               float* __restrict__ Cf, int ldc, int N,
               ushort* __restrict__ Cb, int nbf, int nbfPad)
{
    int idx = blockIdx.x * 256 + threadIdx.x;
    if (idx >= M * 128) return;
    int c = idx & 127, r = idx >> 7;
    float v = 0.f;
    for (int s = 0; s < S; ++s) v += P[(size_t)s * M * 128 + idx];
    if (bias) v += bias[c];
    if (c < N) Cf[(size_t)r * ldc + c] = v;
    if (Cb && c < nbfPad) Cb[(size_t)r * nbfPad + c] = (c < nbf) ? f2bf(v) : (ushort)0;
}

// ---------------- depthwise causal conv (K=4) + bias + SiLU (bf16 in/out) ----------------
__global__ __launch_bounds__(256)
void conv_silu(const ushort* __restrict__ xz, const float* __restrict__ cw,
               const float* __restrict__ cb, ushort* __restrict__ xo, int rowsTotal)
{
    int idx = blockIdx.x * 256 + threadIdx.x;
    if (idx >= rowsTotal * DIn) return;
    int d = idx % DIn, row = idx / DIn, l = row % Ll;
    float acc = cb[d];
#pragma unroll
    for (int j = 0; j < Kc; ++j) {
        int lo = l - 3 + j;
        if (lo >= 0) acc = fmaf(cw[d * Kc + j], bf2f(xz[(size_t)(row - 3 + j) * EOc + d]), acc);
    }
    float s = acc / (1.f + __expf(-acc));
    xo[(size_t)row * DIn + d] = f2bf(s);
}

// ---------------- selective scan, chunked, NG=4 (4 states / thread) ----------------
// thread idx = (((b*NCH + c)*DIn + d)*4 + ng); quad of lanes shares (b,c,d)
__global__ __launch_bounds__(256)
void scan_pass1(const float* __restrict__ dt, const ushort* __restrict__ xab,
                const float* __restrict__ xdbl, const float* __restrict__ A_log,
                float* __restrict__ hend, float* __restrict__ Pbuf, int BC)
{
    int idx = blockIdx.x * 256 + threadIdx.x;
    if (idx >= BC * DIn * NCH * 4) return;
    int ng = idx & 3;
    int rest = idx >> 2;
    int d = rest % DIn;
    int t = rest / DIn;
    int c = t % NCH, b = t / NCH;

    float4 alog = *reinterpret_cast<const float4*>(A_log + d * Nn + ng * 4);
    float A[4] = {-__expf(alog.x), -__expf(alog.y), -__expf(alog.z), -__expf(alog.w)};
    float h[4] = {0.f, 0.f, 0.f, 0.f};
    float P[4] = {1.f, 1.f, 1.f, 1.f};

    size_t row = (size_t)b * Ll + c * CH;
    float  dtv = dt[row * DIn + d];
    float  xv  = bf2f(xab[row * DIn + d]);
    float4 bv  = *reinterpret_cast<const float4*>(xdbl + row * XD + Rn + ng * 4);

    for (int l = 0; l < CH; ++l) {
        float dtn = 0.f, xn = 0.f;
        float4 bn = {0.f, 0.f, 0.f, 0.f};
        if (l + 1 < CH) {
            size_t r2 = row + 1;
            dtn = dt[r2 * DIn + d];
            xn  = bf2f(xab[r2 * DIn + d]);
            bn  = *reinterpret_cast<const float4*>(xdbl + r2 * XD + Rn + ng * 4);
        }
        float cx = dtv * xv;
        float bb[4] = {bv.x, bv.y, bv.z, bv.w};
#pragma unroll
        for (int k = 0; k < 4; ++k) {
            float dA = __expf(dtv * A[k]);
            h[k] = fmaf(dA, h[k], cx * bb[k]);
            P[k] *= dA;
        }
        dtv = dtn; xv = xn; bv = bn; ++row;
    }
    size_t o = (size_t)rest * Nn + ng * 4;
    *reinterpret_cast<float4*>(hend + o) = (float4){h[0], h[1], h[2], h[3]};
    *reinterpret_cast<float4*>(Pbuf + o) = (float4){P[0], P[1], P[2], P[3]};
}

__global__ __launch_bounds__(256)
void scan_pass2(const float* __restrict__ hend, const float* __restrict__ Pbuf,
                float* __restrict__ hstart, int BC)
{
    int idx = blockIdx.x * 256 + threadIdx.x;
    if (idx >= BC * DIn * Nn) return;
    int n = idx % Nn;
    int d = (idx / Nn) % DIn;
    int b = idx / (Nn * DIn);
    float hs = 0.f;
    for (int c = 0; c < NCH; ++c) {
        size_t o = (((size_t)b * NCH + c) * DIn + d) * Nn + n;
        hstart[o] = hs;
        hs = fmaf(Pbuf[o], hs, hend[o]);
    }
}

__global__ __launch_bounds__(256)
void scan_pass3(const float* __restrict__ dt, ushort* __restrict__ xab,
                const float* __restrict__ xdbl, const float* __restrict__ A_log,
                const float* __restrict__ Dp, const ushort* __restrict__ xzb,
                const float* __restrict__ hstart, int BC)
{
    int idx = blockIdx.x * 256 + threadIdx.x;
    if (idx >= BC * DIn * NCH * 4) return;
    int ng = idx & 3;
    int rest = idx >> 2;
    int d = rest % DIn;
    int t = rest / DIn;
    int c = t % NCH, b = t / NCH;

    float4 alog = *reinterpret_cast<const float4*>(A_log + d * Nn + ng * 4);
    float A[4] = {-__expf(alog.x), -__expf(alog.y), -__expf(alog.z), -__expf(alog.w)};
    float4 h4 = *reinterpret_cast<const float4*>(hstart + (size_t)rest * Nn + ng * 4);
    float h[4] = {h4.x, h4.y, h4.z, h4.w};
    const float Dd = Dp[d];

    size_t row = (size_t)b * Ll + c * CH;
    float  dtv = dt[row * DIn + d];
    float  xv  = bf2f(xab[row * DIn + d]);
    float  zv  = bf2f(xzb[row * EOc + DIn + d]);
    float4 bv  = *reinterpret_cast<const float4*>(xdbl + row * XD + Rn + ng * 4);
    float4 cv  = *reinterpret_cast<const float4*>(xdbl + row * XD + Rn + Nn + ng * 4);

    for (int l = 0; l < CH; ++l) {
        float dtn = 0.f, xn = 0.f, zn = 0.f;
        float4 bn = {0.f,0.f,0.f,0.f}, cn = {0.f,0.f,0.f,0.f};
        if (l + 1 < CH) {
            size_t r2 = row + 1;
            dtn = dt[r2 * DIn + d];
            xn  = bf2f(xab[r2 * DIn + d]);
            zn  = bf2f(xzb[r2 * EOc + DIn + d]);
            bn  = *reinterpret_cast<const float4*>(xdbl + r2 * XD + Rn + ng * 4);
            cn  = *reinterpret_cast<const float4*>(xdbl + r2 * XD + Rn + Nn + ng * 4);
        }
        float cx = dtv * xv;
        float bb[4] = {bv.x, bv.y, bv.z, bv.w};
        float cc[4] = {cv.x, cv.y, cv.z, cv.w};
        float y = 0.f;
#pragma unroll
        for (int k = 0; k < 4; ++k) {
            float dA = __expf(dtv * A[k]);
            h[k] = fmaf(dA, h[k], cx * bb[k]);
            y = fmaf(h[k], cc[k], y);
        }
        // quad reduce across the 4 ng lanes (consecutive lanes)
        y += __shfl_xor(y, 1);
        y += __shfl_xor(y, 2);
        y = fmaf(xv, Dd, y);
        float sz = zv / (1.f + __expf(-zv));
        if (ng == 0) xab[row * DIn + d] = f2bf(y * sz);
        dtv = dtn; xv = xn; zv = zn; bv = bn; cv = cn; ++row;
    }
}

// ---------------- host launcher ----------------
extern "C" void kernel_launch(void* const* d_in, const int* in_sizes, int n_in,
                              void* d_out, int out_size, void* d_ws, size_t ws_size,
                              hipStream_t stream)
{
    const float* obs        = (const float*)d_in[0];
    const float* w_in       = (const float*)d_in[1];
    const float* b_in       = (const float*)d_in[2];
    const float* in_proj_w  = (const float*)d_in[3];
    const float* conv_w     = (const float*)d_in[4];
    const float* conv_b     = (const float*)d_in[5];
    const float* x_proj_w   = (const float*)d_in[6];
    const float* dt_proj_w  = (const float*)d_in[7];
    const float* dt_proj_b  = (const float*)d_in[8];
    const float* A_log      = (const float*)d_in[9];
    const float* D_skip     = (const float*)d_in[10];
    const float* out_proj_w = (const float*)d_in[11];
    const float* w_out      = (const float*)d_in[12];
    const float* b_out      = (const float*)d_in[13];
    float* out = (float*)d_out;

    auto per_bc = []() -> size_t {
        size_t r = Ll;
        size_t bts = r*EOc*2            // xzb bf16
                   + r*DIn*2            // xab bf16
                   + r*DIn*4            // dtb f32
                   + r*XD*4             // xdb
                   + r*64*2             // dtr
                   + r*DMn*2            // xbuf
                   + r*OBSn*2           // obsb
                   + 3ull*DIn*NCH*Nn*4  // scan aux
                   + 4ull*r*128*4;      // splitK parts
        return bts + 4096;
    };
    const size_t wbytes = WTOT * 2 + 1024;
    int BC = 8;
    while (BC > 1 && wbytes + per_bc() * BC > ws_size) BC >>= 1;

    ushort* WB = (ushort*)d_ws;
    build_wsplit<<<(int)((WQUADS + 255) / 256), 256, 0, stream>>>(
        w_in, in_proj_w, x_proj_w, dt_proj_w, out_proj_w, w_out, WB);

    const size_t WLAY_INP[2] = {WOFF_INP0, WOFF_INP1};
    const size_t WLAY_XP[2]  = {WOFF_XP0,  WOFF_XP1};
    const size_t WLAY_DT[2]  = {WOFF_DT0,  WOFF_DT1};
    const size_t WLAY_OP[2]  = {WOFF_OP0,  WOFF_OP1};

    for (int b0 = 0; b0 < Bb; b0 += BC) {
        const int M = BC * Ll;
        char* base = (char*)d_ws + ((wbytes + 255) & ~(size_t)255);
        auto alloc = [&](size_t bytes) -> char* {
            char* r = base; base += (bytes + 255) & ~(size_t)255; return r;
        };
        ushort* xzb   = (ushort*)alloc((size_t)M * EOc * 2);
        ushort* xab   = (ushort*)alloc((size_t)M * DIn * 2);
        float*  dtb   = (float*) alloc((size_t)M * DIn * 4);
        float*  xdb   = (float*) alloc((size_t)M * XD * 4);
        ushort* dtr   = (ushort*)alloc((size_t)M * 64 * 2);
        ushort* xbuf  = (ushort*)alloc((size_t)M * DMn * 2);
        ushort* obsb  = (ushort*)alloc((size_t)M * OBSn * 2);
        const size_t sseg = (size_t)BC * DIn * NCH * Nn;
        float*  hend  = (float*) alloc(sseg * 4);
        float*  Pb    = (float*) alloc(sseg * 4);
        float*  hst   = (float*) alloc(sseg * 4);
        float*  parts = (float*) alloc(4ull * M * 128 * 4);

        build_bf<<<(M * OBSn / 4 + 255) / 256, 256, 0, stream>>>(
            obs + (size_t)b0 * Ll * OBSn, obsb, M * OBSn / 4);
        // in_proj -> bf16 xbuf
        gemm_ws<64, 1, 0><<<dim3(6, M / 64), 256, 0, stream>>>(
            obsb, OBSn, WB + WOFF_WIN, b_in, nullptr, xbuf, DMn, M, DMn, 64, 64);

        for (int layer = 0; layer < NLn; ++layer) {
            const float* cw     = conv_w    + (size_t)layer * DIn * Kc;
            const float* cb     = conv_b    + (size_t)layer * DIn;
            const float* dtbias = dt_proj_b + (size_t)layer * DIn;
            const float* Al     = A_log     + (size_t)layer * DIn * Nn;
            const float* Dpp    = D_skip    + (size_t)layer * DIn;

            // xz -> bf16 [M x 3072]
            gemm_ws<128, 1, 0><<<dim3(24, M / 128), 256, 0, stream>>>(
                xbuf, DMn, WB + WLAY_INP[layer], nullptr, nullptr, xzb, EOc, M, EOc, DMn, DMn);
            // conv + SiLU -> bf16 xab
            conv_silu<<<(M * DIn + 255) / 256, 256, 0, stream>>>(xzb, cw, cb, xab, M);
            // x_proj: split-K S=4 -> xdb f32 + dtr bf16 (pad 64)
            gemm_ws<64, 0, 1><<<dim3(1, M / 64, 4), 256, 0, stream>>>(
                xab, DIn, WB + WLAY_XP[layer], nullptr, parts, nullptr, 128, M, 128, DIn, DIn / 4);
            reduce_sk<<<(M * 128 + 255) / 256, 256, 0, stream>>>(
                parts, 4, M, nullptr, xdb, XD, XD, dtr, Rn, 64);
            // dt = softplus(...) -> f32
            gemm_ws<64, 2, 0><<<dim3(12, M / 64), 256, 0, stream>>>(
                dtr, 64, WB + WLAY_DT[layer], dtbias, dtb, nullptr, DIn, M, DIn, 64, 64);
            // selective scan
            {
                int tot1 = BC * DIn * NCH * 4;
                scan_pass1<<<(tot1 + 255) / 256, 256, 0, stream>>>(dtb, xab, xdb, Al, hend, Pb, BC);
                int tot2 = BC * DIn * Nn;
                scan_pass2<<<(tot2 + 255) / 256, 256, 0, stream>>>(hend, Pb, hst, BC);
                scan_pass3<<<(tot1 + 255) / 256, 256, 0, stream>>>(dtb, xab, xdb, Al, Dpp, xzb, hst, BC);
            }
            // out_proj -> bf16 xbuf
            gemm_ws<64, 1, 0><<<dim3(6, M / 64), 256, 0, stream>>>(
                xab, DIn, WB + WLAY_OP[layer], nullptr, nullptr, xbuf, DMn, M, DMn, DIn, DIn);
        }
        // head: split-K S=4
        gemm_ws<64, 0, 1><<<dim3(1, M / 64, 4), 256, 0, stream>>>(
            xbuf, DMn, WB + WOFF_WOUT, nullptr, parts, nullptr, 128, M, 128, DMn, DMn / 4);
        reduce_sk<<<(M * 128 + 255) / 256, 256, 0, stream>>>(
            parts, 4, M, b_out, out + (size_t)b0 * Ll * ACTn, ACTn, ACTn, nullptr, 0, 0);
    }
}

// Round 5
// 1664.899 us; speedup vs baseline: 4.4808x; 1.0259x over previous
//
#include <hip/hip_runtime.h>
#include <cstddef>

// ---------------- problem constants ----------------
constexpr int Bb  = 8;
constexpr int Ll  = 2048;
constexpr int OBSn = 64;
constexpr int ACTn = 16;
constexpr int DMn = 768;
constexpr int DIn = 1536;
constexpr int Nn  = 16;
constexpr int Rn  = 48;
constexpr int Kc  = 4;
constexpr int NLn = 2;
constexpr int XD  = Rn + 2 * Nn;   // 80
constexpr int CH  = 128;
constexpr int NCH = Ll / CH;       // 16
constexpr int EOc = 2 * DIn;       // 3072

typedef __attribute__((ext_vector_type(8))) short short8v;
typedef __attribute__((ext_vector_type(4))) float f32x4;

__device__ inline ushort f2bf(float f) {
    uint u = __float_as_uint(f);
    return (ushort)((u + 0x7FFFu + ((u >> 16) & 1u)) >> 16);   // RNE
}
__device__ inline float bf2f(ushort b) { return __uint_as_float(((uint)b) << 16); }

// ---------------- W' builder: all weights -> [Whi | Wlo] bf16, once ----------------
constexpr size_t WOFF_WIN = 0, WOFF_INP0 = 98304, WOFF_INP1 = 4816896,
                 WOFF_XP0 = 9535488, WOFF_XP1 = 9928704, WOFF_DT0 = 10321920,
                 WOFF_DT1 = 10518528, WOFF_OP0 = 10715136, WOFF_OP1 = 13074432,
                 WOFF_WOUT = 15433728, WTOT = 15630336;   // ushorts
constexpr size_t WQUADS = WTOT / 4;

__global__ __launch_bounds__(256)
void build_wsplit(const float* __restrict__ w_in, const float* __restrict__ inp,
                  const float* __restrict__ xp,  const float* __restrict__ dtp,
                  const float* __restrict__ op,  const float* __restrict__ wout,
                  ushort* __restrict__ WB)
{
    constexpr int NS = 10;
    constexpr int    sSel[NS] = {0,1,1,2,2,3,3,4,4,5};
    constexpr size_t sOff[NS] = {0, 0, 3072ull*768, 0, 80ull*1536, 0, 1536ull*48, 0, 768ull*1536, 0};
    constexpr int    sN[NS]   = {768,3072,3072,80,80,1536,1536,768,768,16};
    constexpr int    sK[NS]   = {64,768,768,1536,1536,48,48,1536,1536,768};
    constexpr int    sKp[NS]  = {64,768,768,1536,1536,64,64,1536,1536,768};
    constexpr size_t sD[NS]   = {WOFF_WIN,WOFF_INP0,WOFF_INP1,WOFF_XP0,WOFF_XP1,
                                 WOFF_DT0,WOFF_DT1,WOFF_OP0,WOFF_OP1,WOFF_WOUT};
    constexpr size_t sQ[NS+1] = {0,24576,1204224,2383872,2482176,2580480,
                                 2629632,2678784,3268608,3858432,3907584};

    size_t qid = (size_t)blockIdx.x * 256 + threadIdx.x;
    if (qid >= sQ[NS]) return;
    int s = 0;
#pragma unroll
    for (int i = 0; i < NS; ++i) if (qid >= sQ[i+1]) s = i + 1;

    size_t local = qid - sQ[s];
    const int Kp = sKp[s], K = sK[s], N = sN[s];
    const int ncol4 = (2 * Kp) >> 2;
    const int n  = (int)(local / ncol4);
    const int c4 = (int)(local % ncol4) * 4;
    const bool lo = (c4 >= Kp);
    const int sc = lo ? c4 - Kp : c4;
    ushort4 o; o.x = o.y = o.z = o.w = 0;
    if (n < N && sc < K) {
        const float* src;
        switch (sSel[s]) { case 0: src = w_in; break; case 1: src = inp; break;
                           case 2: src = xp;   break; case 3: src = dtp; break;
                           case 4: src = op;   break; default: src = wout; }
        float4 v = *reinterpret_cast<const float4*>(src + sOff[s] + (size_t)n * K + sc);
        ushort h0 = f2bf(v.x), h1 = f2bf(v.y), h2 = f2bf(v.z), h3 = f2bf(v.w);
        if (lo) {
            h0 = f2bf(v.x - bf2f(h0)); h1 = f2bf(v.y - bf2f(h1));
            h2 = f2bf(v.z - bf2f(h2)); h3 = f2bf(v.w - bf2f(h3));
        }
        o.x = h0; o.y = h1; o.z = h2; o.w = h3;
    }
    *reinterpret_cast<ushort4*>(WB + sD[s] + (size_t)n * (2 * Kp) + c4) = o;
}

__global__ __launch_bounds__(256)
void build_bf(const float* __restrict__ src, ushort* __restrict__ dst, int n4)
{
    int i = blockIdx.x * 256 + threadIdx.x;
    if (i >= n4) return;
    float4 v = *reinterpret_cast<const float4*>(src + (size_t)i * 4);
    ushort4 o; o.x = f2bf(v.x); o.y = f2bf(v.y); o.z = f2bf(v.z); o.w = f2bf(v.w);
    *reinterpret_cast<ushort4*>(dst + (size_t)i * 4) = o;
}

// ---------------- MFMA GEMM (A bf16 [MxKp], W' [Npad x 2Kp]) ----------------
// OUT: 0=f32, 1=bf16, 2=softplus f32, 4=softplus bf16. SPLITK: raw partials.
template<int BM, int OUT, int SPLITK>
__global__ __launch_bounds__(256)
void gemm_ws(const ushort* __restrict__ Ap, int lda,
             const ushort* __restrict__ Wp,
             const float* __restrict__ bias,
             float* __restrict__ Cf, ushort* __restrict__ Cb, int ldc,
             int M, int N, int Kp, int ktLen)
{
    constexpr int MI = BM / 32;
    __shared__ ushort As[BM * 32];
    __shared__ ushort Ws2[8192];

    const int nwgx = gridDim.x;
    const int nwg  = nwgx * gridDim.y;
    int bid = blockIdx.y * nwgx + blockIdx.x;
    {   // bijective XCD swizzle
        int q = nwg >> 3, r = nwg & 7;
        int x = bid & 7, lc = bid >> 3;
        bid = (x < r ? x * (q + 1) : r * (q + 1) + (x - r) * q) + lc;
    }
    const int col0 = (bid % nwgx) * 128;
    const int row0 = (bid / nwgx) * BM;

    const int tid = threadIdx.x, w = tid >> 6, lane = tid & 63;
    const int wr = w >> 1, wc = w & 1, half = lane >> 4, lid = lane & 15;

    f32x4 acc[MI][4];
#pragma unroll
    for (int i = 0; i < MI; ++i)
#pragma unroll
        for (int j = 0; j < 4; ++j) acc[i][j] = (f32x4){0.f, 0.f, 0.f, 0.f};

    const int gr = lane >> 2, gc8 = (lane & 3) * 8;
    const int ldw = 2 * Kp;
    const int kt0 = SPLITK ? blockIdx.z * ktLen : 0;

    for (int kt = kt0; kt < kt0 + ktLen; kt += 32) {
        if constexpr (BM == 128) {
#pragma unroll
            for (int j = 0; j < 2; ++j) {
                int g = w * 2 + j;
                __builtin_amdgcn_global_load_lds(
                    (const __attribute__((address_space(1))) uint*)(Ap + (size_t)(row0 + g*16 + gr) * lda + kt + gc8),
                    (__attribute__((address_space(3))) uint*)(&As[g * 512]), 16, 0, 0);
            }
        } else {
            int g = w;
            __builtin_amdgcn_global_load_lds(
                (const __attribute__((address_space(1))) uint*)(Ap + (size_t)(row0 + g*16 + gr) * lda + kt + gc8),
                (__attribute__((address_space(3))) uint*)(&As[g * 512]), 16, 0, 0);
        }
#pragma unroll
        for (int j = 0; j < 2; ++j) {
            int g = w * 2 + j;
            const ushort* wsrc = Wp + (size_t)(col0 + g*16 + gr) * ldw + kt + gc8;
            __builtin_amdgcn_global_load_lds(
                (const __attribute__((address_space(1))) uint*)wsrc,
                (__attribute__((address_space(3))) uint*)(&Ws2[g * 512]), 16, 0, 0);
            __builtin_amdgcn_global_load_lds(
                (const __attribute__((address_space(1))) uint*)(wsrc + Kp),
                (__attribute__((address_space(3))) uint*)(&Ws2[4096 + g * 512]), 16, 0, 0);
        }
        __syncthreads();

        short8v a[MI], bh[4], bl[4];
#pragma unroll
        for (int mi = 0; mi < MI; ++mi)
            a[mi] = *reinterpret_cast<const short8v*>(&As[(wr*(BM/2) + mi*16 + lid) * 32 + half * 8]);
#pragma unroll
        for (int ni = 0; ni < 4; ++ni) {
            bh[ni] = *reinterpret_cast<const short8v*>(&Ws2[(wc*64 + ni*16 + lid) * 32 + half * 8]);
            bl[ni] = *reinterpret_cast<const short8v*>(&Ws2[4096 + (wc*64 + ni*16 + lid) * 32 + half * 8]);
        }
#pragma unroll
        for (int mi = 0; mi < MI; ++mi)
#pragma unroll
            for (int ni = 0; ni < 4; ++ni)
                acc[mi][ni] = __builtin_amdgcn_mfma_f32_16x16x32_bf16(a[mi], bh[ni], acc[mi][ni], 0, 0, 0);
#pragma unroll
        for (int mi = 0; mi < MI; ++mi)
#pragma unroll
            for (int ni = 0; ni < 4; ++ni)
                acc[mi][ni] = __builtin_amdgcn_mfma_f32_16x16x32_bf16(a[mi], bl[ni], acc[mi][ni], 0, 0, 0);
        __syncthreads();
    }

    if constexpr (SPLITK) {
        float* P = Cf + (size_t)blockIdx.z * M * 128;
#pragma unroll
        for (int mi = 0; mi < MI; ++mi) {
            int r = row0 + wr*(BM/2) + mi*16 + half*4;
#pragma unroll
            for (int ni = 0; ni < 4; ++ni) {
                int c = col0 + wc*64 + ni*16 + lid;
#pragma unroll
                for (int q = 0; q < 4; ++q)
                    P[(size_t)(r + q) * 128 + c] = acc[mi][ni][q];
            }
        }
    } else {
#pragma unroll
        for (int mi = 0; mi < MI; ++mi) {
            int r = row0 + wr*(BM/2) + mi*16 + half*4;
#pragma unroll
            for (int ni = 0; ni < 4; ++ni) {
                int c = col0 + wc*64 + ni*16 + lid;
                if (c >= N) continue;
                float bv = bias ? bias[c] : 0.f;
#pragma unroll
                for (int q = 0; q < 4; ++q) {
                    float v = acc[mi][ni][q] + bv;
                    if constexpr (OUT == 2 || OUT == 4) v = (v > 20.f) ? v : log1pf(__expf(v));
                    if constexpr (OUT == 1 || OUT == 4) Cb[(size_t)(r + q) * ldc + c] = f2bf(v);
                    else                                Cf[(size_t)(r + q) * ldc + c] = v;
                }
            }
        }
    }
}

// ---------------- split-K reduce: f32 out / bf16 mirror / packed B,C ----------------
__global__ __launch_bounds__(256)
void reduce_sk(const float* __restrict__ P, int S, int M,
               const float* __restrict__ bias,
               float* __restrict__ Cf, int ldc, int N,
               ushort* __restrict__ Cb, int nbf, int nbfPad,
               float* __restrict__ Bcp)
{
    int idx = blockIdx.x * 256 + threadIdx.x;
    if (idx >= M * 128) return;
    int c = idx & 127, r = idx >> 7;
    float v = 0.f;
    for (int s = 0; s < S; ++s) v += P[(size_t)s * M * 128 + idx];
    if (bias) v += bias[c];
    if (Cf && c < N) Cf[(size_t)r * ldc + c] = v;
    if (Cb && c < nbfPad) Cb[(size_t)r * nbfPad + c] = (c < nbf) ? f2bf(v) : (ushort)0;
    if (Bcp && c >= Rn && c < Rn + 2 * Nn) Bcp[(size_t)r * 32 + (c - Rn)] = v;
}

// ---------------- depthwise causal conv (K=4) + bias + SiLU, x4 vectorized ----------------
__global__ __launch_bounds__(256)
void conv_silu(const ushort* __restrict__ xz, const float* __restrict__ cw,
               const float* __restrict__ cb, ushort* __restrict__ xo, int rowsTotal)
{
    constexpr int ND4 = DIn / 4;
    int idx = blockIdx.x * 256 + threadIdx.x;
    if (idx >= rowsTotal * ND4) return;
    int d4 = (idx % ND4) * 4, row = idx / ND4, l = row % Ll;
    float4 cbv = *reinterpret_cast<const float4*>(cb + d4);
    float acc[4] = {cbv.x, cbv.y, cbv.z, cbv.w};
    float4 w0 = *reinterpret_cast<const float4*>(cw + (d4 + 0) * 4);
    float4 w1 = *reinterpret_cast<const float4*>(cw + (d4 + 1) * 4);
    float4 w2 = *reinterpret_cast<const float4*>(cw + (d4 + 2) * 4);
    float4 w3 = *reinterpret_cast<const float4*>(cw + (d4 + 3) * 4);
    const float* wv[4] = {(const float*)&w0, (const float*)&w1,
                          (const float*)&w2, (const float*)&w3};
#pragma unroll
    for (int j = 0; j < Kc; ++j) {
        int lo = l - 3 + j;
        if (lo >= 0) {
            ushort4 xv = *reinterpret_cast<const ushort4*>(xz + (size_t)(row - 3 + j) * EOc + d4);
            acc[0] = fmaf(wv[0][j], bf2f(xv.x), acc[0]);
            acc[1] = fmaf(wv[1][j], bf2f(xv.y), acc[1]);
            acc[2] = fmaf(wv[2][j], bf2f(xv.z), acc[2]);
            acc[3] = fmaf(wv[3][j], bf2f(xv.w), acc[3]);
        }
    }
    ushort4 o;
    o.x = f2bf(acc[0] / (1.f + __expf(-acc[0])));
    o.y = f2bf(acc[1] / (1.f + __expf(-acc[1])));
    o.z = f2bf(acc[2] / (1.f + __expf(-acc[2])));
    o.w = f2bf(acc[3] / (1.f + __expf(-acc[3])));
    *reinterpret_cast<ushort4*>(xo + (size_t)row * DIn + d4) = o;
}

// ---------------- selective scan, chunked, NG=4 (4 states / thread) ----------------
__global__ __launch_bounds__(256)
void scan_pass1(const ushort* __restrict__ dtb, const ushort* __restrict__ xab,
                const float* __restrict__ bcp, const float* __restrict__ A_log,
                float* __restrict__ hend, float* __restrict__ Pbuf, int BC)
{
    int idx = blockIdx.x * 256 + threadIdx.x;
    if (idx >= BC * DIn * NCH * 4) return;
    int ng = idx & 3;
    int rest = idx >> 2;
    int d = rest % DIn;
    int t = rest / DIn;
    int c = t % NCH, b = t / NCH;

    float4 alog = *reinterpret_cast<const float4*>(A_log + d * Nn + ng * 4);
    float A[4] = {-__expf(alog.x), -__expf(alog.y), -__expf(alog.z), -__expf(alog.w)};
    float h[4] = {0.f, 0.f, 0.f, 0.f};
    float S = 0.f;

    size_t row = (size_t)b * Ll + c * CH;
    float  dtv = bf2f(dtb[row * DIn + d]);
    float  xv  = bf2f(xab[row * DIn + d]);
    float4 bv  = *reinterpret_cast<const float4*>(bcp + row * 32 + ng * 4);

    for (int l = 0; l < CH; ++l) {
        float dtn = 0.f, xn = 0.f;
        float4 bn = {0.f, 0.f, 0.f, 0.f};
        if (l + 1 < CH) {
            size_t r2 = row + 1;
            dtn = bf2f(dtb[r2 * DIn + d]);
            xn  = bf2f(xab[r2 * DIn + d]);
            bn  = *reinterpret_cast<const float4*>(bcp + r2 * 32 + ng * 4);
        }
        float cx = dtv * xv;
        S += dtv;
        float bb[4] = {bv.x, bv.y, bv.z, bv.w};
#pragma unroll
        for (int k = 0; k < 4; ++k) {
            float dA = __expf(dtv * A[k]);
            h[k] = fmaf(dA, h[k], cx * bb[k]);
        }
        dtv = dtn; xv = xn; bv = bn; ++row;
    }
    size_t o = (size_t)rest * Nn + ng * 4;
    *reinterpret_cast<float4*>(hend + o) = (float4){h[0], h[1], h[2], h[3]};
    *reinterpret_cast<float4*>(Pbuf + o) =
        (float4){__expf(A[0] * S), __expf(A[1] * S), __expf(A[2] * S), __expf(A[3] * S)};
}

__global__ __launch_bounds__(256)
void scan_pass2(const float* __restrict__ hend, const float* __restrict__ Pbuf,
                float* __restrict__ hstart, int BC)
{
    int idx = blockIdx.x * 256 + threadIdx.x;
    if (idx >= BC * DIn * Nn) return;
    int n = idx % Nn;
    int d = (idx / Nn) % DIn;
    int b = idx / (Nn * DIn);
    float hs = 0.f;
    for (int c = 0; c < NCH; ++c) {
        size_t o = (((size_t)b * NCH + c) * DIn + d) * Nn + n;
        hstart[o] = hs;
        hs = fmaf(Pbuf[o], hs, hend[o]);
    }
}

__global__ __launch_bounds__(256)
void scan_pass3(const ushort* __restrict__ dtb, ushort* __restrict__ xab,
                const float* __restrict__ bcp, const float* __restrict__ A_log,
                const float* __restrict__ Dp, const ushort* __restrict__ xzb,
                const float* __restrict__ hstart, int BC)
{
    int idx = blockIdx.x * 256 + threadIdx.x;
    if (idx >= BC * DIn * NCH * 4) return;
    int ng = idx & 3;
    int rest = idx >> 2;
    int d = rest % DIn;
    int t = rest / DIn;
    int c = t % NCH, b = t / NCH;

    float4 alog = *reinterpret_cast<const float4*>(A_log + d * Nn + ng * 4);
    float A[4] = {-__expf(alog.x), -__expf(alog.y), -__expf(alog.z), -__expf(alog.w)};
    float4 h4 = *reinterpret_cast<const float4*>(hstart + (size_t)rest * Nn + ng * 4);
    float h[4] = {h4.x, h4.y, h4.z, h4.w};
    const float Dd = Dp[d];

    size_t row = (size_t)b * Ll + c * CH;
    float  dtv = bf2f(dtb[row * DIn + d]);
    float  xv  = bf2f(xab[row * DIn + d]);
    float  zv  = bf2f(xzb[row * EOc + DIn + d]);
    float4 bv  = *reinterpret_cast<const float4*>(bcp + row * 32 + ng * 4);
    float4 cv  = *reinterpret_cast<const float4*>(bcp + row * 32 + 16 + ng * 4);

    for (int l = 0; l < CH; ++l) {
        float dtn = 0.f, xn = 0.f, zn = 0.f;
        float4 bn = {0.f,0.f,0.f,0.f}, cn = {0.f,0.f,0.f,0.f};
        if (l + 1 < CH) {
            size_t r2 = row + 1;
            dtn = bf2f(dtb[r2 * DIn + d]);
            xn  = bf2f(xab[r2 * DIn + d]);
            zn  = bf2f(xzb[r2 * EOc + DIn + d]);
            bn  = *reinterpret_cast<const float4*>(bcp + r2 * 32 + ng * 4);
            cn  = *reinterpret_cast<const float4*>(bcp + r2 * 32 + 16 + ng * 4);
        }
        float cx = dtv * xv;
        float bb[4] = {bv.x, bv.y, bv.z, bv.w};
        float cc[4] = {cv.x, cv.y, cv.z, cv.w};
        float y = 0.f;
#pragma unroll
        for (int k = 0; k < 4; ++k) {
            float dA = __expf(dtv * A[k]);
            h[k] = fmaf(dA, h[k], cx * bb[k]);
            y = fmaf(h[k], cc[k], y);
        }
        y += __shfl_xor(y, 1);
        y += __shfl_xor(y, 2);
        y = fmaf(xv, Dd, y);
        float sz = zv / (1.f + __expf(-zv));
        if (ng == 0) xab[row * DIn + d] = f2bf(y * sz);
        dtv = dtn; xv = xn; zv = zn; bv = bn; cv = cn; ++row;
    }
}

// ---------------- host launcher ----------------
extern "C" void kernel_launch(void* const* d_in, const int* in_sizes, int n_in,
                              void* d_out, int out_size, void* d_ws, size_t ws_size,
                              hipStream_t stream)
{
    const float* obs        = (const float*)d_in[0];
    const float* w_in       = (const float*)d_in[1];
    const float* b_in       = (const float*)d_in[2];
    const float* in_proj_w  = (const float*)d_in[3];
    const float* conv_w     = (const float*)d_in[4];
    const float* conv_b     = (const float*)d_in[5];
    const float* x_proj_w   = (const float*)d_in[6];
    const float* dt_proj_w  = (const float*)d_in[7];
    const float* dt_proj_b  = (const float*)d_in[8];
    const float* A_log      = (const float*)d_in[9];
    const float* D_skip     = (const float*)d_in[10];
    const float* out_proj_w = (const float*)d_in[11];
    const float* w_out      = (const float*)d_in[12];
    const float* b_out      = (const float*)d_in[13];
    float* out = (float*)d_out;

    auto per_bc = []() -> size_t {
        size_t r = Ll;
        size_t bts = r*EOc*2            // xzb bf16
                   + r*DIn*2            // xab bf16
                   + r*DIn*2            // dtbb bf16
                   + r*32*4             // bcp f32 packed B,C
                   + r*64*2             // dtr
                   + r*DMn*2            // xbuf
                   + r*OBSn*2           // obsb
                   + 3ull*DIn*NCH*Nn*4  // scan aux
                   + 4ull*r*128*4;      // splitK parts
        return bts + 8192;
    };
    const size_t wbytes = WTOT * 2 + 1024;
    int BC = 8;
    while (BC > 1 && wbytes + per_bc() * BC > ws_size) BC >>= 1;

    ushort* WB = (ushort*)d_ws;
    build_wsplit<<<(int)((WQUADS + 255) / 256), 256, 0, stream>>>(
        w_in, in_proj_w, x_proj_w, dt_proj_w, out_proj_w, w_out, WB);

    const size_t WLAY_INP[2] = {WOFF_INP0, WOFF_INP1};
    const size_t WLAY_XP[2]  = {WOFF_XP0,  WOFF_XP1};
    const size_t WLAY_DT[2]  = {WOFF_DT0,  WOFF_DT1};
    const size_t WLAY_OP[2]  = {WOFF_OP0,  WOFF_OP1};

    for (int b0 = 0; b0 < Bb; b0 += BC) {
        const int M = BC * Ll;
        char* base = (char*)d_ws + ((wbytes + 255) & ~(size_t)255);
        auto alloc = [&](size_t bytes) -> char* {
            char* r = base; base += (bytes + 255) & ~(size_t)255; return r;
        };
        ushort* xzb   = (ushort*)alloc((size_t)M * EOc * 2);
        ushort* xab   = (ushort*)alloc((size_t)M * DIn * 2);
        ushort* dtbb  = (ushort*)alloc((size_t)M * DIn * 2);
        float*  bcp   = (float*) alloc((size_t)M * 32 * 4);
        ushort* dtr   = (ushort*)alloc((size_t)M * 64 * 2);
        ushort* xbuf  = (ushort*)alloc((size_t)M * DMn * 2);
        ushort* obsb  = (ushort*)alloc((size_t)M * OBSn * 2);
        const size_t sseg = (size_t)BC * DIn * NCH * Nn;
        float*  hend  = (float*) alloc(sseg * 4);
        float*  Pb    = (float*) alloc(sseg * 4);
        float*  hst   = (float*) alloc(sseg * 4);
        float*  parts = (float*) alloc(4ull * M * 128 * 4);

        build_bf<<<(M * OBSn / 4 + 255) / 256, 256, 0, stream>>>(
            obs + (size_t)b0 * Ll * OBSn, obsb, M * OBSn / 4);
        // in_proj -> bf16 xbuf
        gemm_ws<64, 1, 0><<<dim3(6, M / 64), 256, 0, stream>>>(
            obsb, OBSn, WB + WOFF_WIN, b_in, nullptr, xbuf, DMn, M, DMn, 64, 64);

        for (int layer = 0; layer < NLn; ++layer) {
            const float* cw     = conv_w    + (size_t)layer * DIn * Kc;
            const float* cb     = conv_b    + (size_t)layer * DIn;
            const float* dtbias = dt_proj_b + (size_t)layer * DIn;
            const float* Al     = A_log     + (size_t)layer * DIn * Nn;
            const float* Dpp    = D_skip    + (size_t)layer * DIn;

            // xz -> bf16 [M x 3072]
            gemm_ws<128, 1, 0><<<dim3(24, M / 128), 256, 0, stream>>>(
                xbuf, DMn, WB + WLAY_INP[layer], nullptr, nullptr, xzb, EOc, M, EOc, DMn, DMn);
            // conv + SiLU -> bf16 xab
            conv_silu<<<(M * (DIn / 4) + 255) / 256, 256, 0, stream>>>(xzb, cw, cb, xab, M);
            // x_proj: split-K S=4 -> parts -> dtr bf16 (pad 64) + packed B,C f32
            gemm_ws<64, 0, 1><<<dim3(1, M / 64, 4), 256, 0, stream>>>(
                xab, DIn, WB + WLAY_XP[layer], nullptr, parts, nullptr, 128, M, 128, DIn, DIn / 4);
            reduce_sk<<<(M * 128 + 255) / 256, 256, 0, stream>>>(
                parts, 4, M, nullptr, nullptr, 0, 0, dtr, Rn, 64, bcp);
            // dt = softplus(...) -> bf16
            gemm_ws<64, 4, 0><<<dim3(12, M / 64), 256, 0, stream>>>(
                dtr, 64, WB + WLAY_DT[layer], dtbias, nullptr, dtbb, DIn, M, DIn, 64, 64);
            // selective scan
            {
                int tot1 = BC * DIn * NCH * 4;
                scan_pass1<<<(tot1 + 255) / 256, 256, 0, stream>>>(dtbb, xab, bcp, Al, hend, Pb, BC);
                int tot2 = BC * DIn * Nn;
                scan_pass2<<<(tot2 + 255) / 256, 256, 0, stream>>>(hend, Pb, hst, BC);
                scan_pass3<<<(tot1 + 255) / 256, 256, 0, stream>>>(dtbb, xab, bcp, Al, Dpp, xzb, hst, BC);
            }
            // out_proj -> bf16 xbuf
            gemm_ws<64, 1, 0><<<dim3(6, M / 64), 256, 0, stream>>>(
                xab, DIn, WB + WLAY_OP[layer], nullptr, nullptr, xbuf, DMn, M, DMn, DIn, DIn);
        }
        // head: split-K S=4
        gemm_ws<64, 0, 1><<<dim3(1, M / 64, 4), 256, 0, stream>>>(
            xbuf, DMn, WB + WOFF_WOUT, nullptr, parts, nullptr, 128, M, 128, DMn, DMn / 4);
        reduce_sk<<<(M * 128 + 255) / 256, 256, 0, stream>>>(
            parts, 4, M, b_out, out + (size_t)b0 * Ll * ACTn, ACTn, ACTn, nullptr, 0, 0, nullptr);
    }
}

// Round 6
// 1475.446 us; speedup vs baseline: 5.0561x; 1.1284x over previous
//
#include <hip/hip_runtime.h>
#include <cstddef>

// ---------------- problem constants ----------------
constexpr int Bb  = 8;
constexpr int Ll  = 2048;
constexpr int OBSn = 64;
constexpr int ACTn = 16;
constexpr int DMn = 768;
constexpr int DIn = 1536;
constexpr int Nn  = 16;
constexpr int Rn  = 48;
constexpr int Kc  = 4;
constexpr int NLn = 2;
constexpr int XD  = Rn + 2 * Nn;   // 80
constexpr int CH  = 128;
constexpr int NCH = Ll / CH;       // 16
constexpr int EOc = 2 * DIn;       // 3072
constexpr float L2E = 1.4426950408889634f;

typedef __attribute__((ext_vector_type(8))) short short8v;
typedef __attribute__((ext_vector_type(4))) float f32x4;

__device__ inline ushort f2bf(float f) {
    uint u = __float_as_uint(f);
    return (ushort)((u + 0x7FFFu + ((u >> 16) & 1u)) >> 16);   // RNE
}
__device__ inline float bf2f(ushort b) { return __uint_as_float(((uint)b) << 16); }
__device__ inline float exp2a(float x) {            // raw v_exp_f32: D = 2^x
    float r; asm("v_exp_f32 %0, %1" : "=v"(r) : "v"(x)); return r;
}

// ---------------- W' builder: all weights -> [Whi | Wlo] bf16, once ----------------
constexpr size_t WOFF_WIN = 0, WOFF_INP0 = 98304, WOFF_INP1 = 4816896,
                 WOFF_XP0 = 9535488, WOFF_XP1 = 9928704, WOFF_DT0 = 10321920,
                 WOFF_DT1 = 10518528, WOFF_OP0 = 10715136, WOFF_OP1 = 13074432,
                 WOFF_WOUT = 15433728, WTOT = 15630336;   // ushorts
constexpr size_t WQUADS = WTOT / 4;

__global__ __launch_bounds__(256)
void build_wsplit(const float* __restrict__ w_in, const float* __restrict__ inp,
                  const float* __restrict__ xp,  const float* __restrict__ dtp,
                  const float* __restrict__ op,  const float* __restrict__ wout,
                  ushort* __restrict__ WB)
{
    constexpr int NS = 10;
    constexpr int    sSel[NS] = {0,1,1,2,2,3,3,4,4,5};
    constexpr size_t sOff[NS] = {0, 0, 3072ull*768, 0, 80ull*1536, 0, 1536ull*48, 0, 768ull*1536, 0};
    constexpr int    sN[NS]   = {768,3072,3072,80,80,1536,1536,768,768,16};
    constexpr int    sK[NS]   = {64,768,768,1536,1536,48,48,1536,1536,768};
    constexpr int    sKp[NS]  = {64,768,768,1536,1536,64,64,1536,1536,768};
    constexpr size_t sD[NS]   = {WOFF_WIN,WOFF_INP0,WOFF_INP1,WOFF_XP0,WOFF_XP1,
                                 WOFF_DT0,WOFF_DT1,WOFF_OP0,WOFF_OP1,WOFF_WOUT};
    constexpr size_t sQ[NS+1] = {0,24576,1204224,2383872,2482176,2580480,
                                 2629632,2678784,3268608,3858432,3907584};

    size_t qid = (size_t)blockIdx.x * 256 + threadIdx.x;
    if (qid >= sQ[NS]) return;
    int s = 0;
#pragma unroll
    for (int i = 0; i < NS; ++i) if (qid >= sQ[i+1]) s = i + 1;

    size_t local = qid - sQ[s];
    const int Kp = sKp[s], K = sK[s], N = sN[s];
    const int ncol4 = (2 * Kp) >> 2;
    const int n  = (int)(local / ncol4);
    const int c4 = (int)(local % ncol4) * 4;
    const bool lo = (c4 >= Kp);
    const int sc = lo ? c4 - Kp : c4;
    ushort4 o; o.x = o.y = o.z = o.w = 0;
    if (n < N && sc < K) {
        const float* src;
        switch (sSel[s]) { case 0: src = w_in; break; case 1: src = inp; break;
                           case 2: src = xp;   break; case 3: src = dtp; break;
                           case 4: src = op;   break; default: src = wout; }
        float4 v = *reinterpret_cast<const float4*>(src + sOff[s] + (size_t)n * K + sc);
        ushort h0 = f2bf(v.x), h1 = f2bf(v.y), h2 = f2bf(v.z), h3 = f2bf(v.w);
        if (lo) {
            h0 = f2bf(v.x - bf2f(h0)); h1 = f2bf(v.y - bf2f(h1));
            h2 = f2bf(v.z - bf2f(h2)); h3 = f2bf(v.w - bf2f(h3));
        }
        o.x = h0; o.y = h1; o.z = h2; o.w = h3;
    }
    *reinterpret_cast<ushort4*>(WB + sD[s] + (size_t)n * (2 * Kp) + c4) = o;
}

__global__ __launch_bounds__(256)
void build_bf(const float* __restrict__ src, ushort* __restrict__ dst, int n4)
{
    int i = blockIdx.x * 256 + threadIdx.x;
    if (i >= n4) return;
    float4 v = *reinterpret_cast<const float4*>(src + (size_t)i * 4);
    ushort4 o; o.x = f2bf(v.x); o.y = f2bf(v.y); o.z = f2bf(v.z); o.w = f2bf(v.w);
    *reinterpret_cast<ushort4*>(dst + (size_t)i * 4) = o;
}

// ---------------- MFMA GEMM (A bf16 [MxKp], W' [Npad x 2Kp]) ----------------
// OUT: 0=f32, 1=bf16, 2=softplus f32, 4=softplus bf16. SPLITK: raw partials.
// WLO=false: use only the hi half of W' (single-bf16 weights).
template<int BM, int OUT, int SPLITK, bool WLO = true>
__global__ __launch_bounds__(256)
void gemm_ws(const ushort* __restrict__ Ap, int lda,
             const ushort* __restrict__ Wp,
             const float* __restrict__ bias,
             float* __restrict__ Cf, ushort* __restrict__ Cb, int ldc,
             int M, int N, int Kp, int ktLen)
{
    constexpr int MI = BM / 32;
    __shared__ ushort As[BM * 32];
    __shared__ ushort Ws2[WLO ? 8192 : 4096];

    const int nwgx = gridDim.x;
    const int nwg  = nwgx * gridDim.y;
    int bid = blockIdx.y * nwgx + blockIdx.x;
    {   // bijective XCD swizzle
        int q = nwg >> 3, r = nwg & 7;
        int x = bid & 7, lc = bid >> 3;
        bid = (x < r ? x * (q + 1) : r * (q + 1) + (x - r) * q) + lc;
    }
    const int col0 = (bid % nwgx) * 128;
    const int row0 = (bid / nwgx) * BM;

    const int tid = threadIdx.x, w = tid >> 6, lane = tid & 63;
    const int wr = w >> 1, wc = w & 1, half = lane >> 4, lid = lane & 15;

    f32x4 acc[MI][4];
#pragma unroll
    for (int i = 0; i < MI; ++i)
#pragma unroll
        for (int j = 0; j < 4; ++j) acc[i][j] = (f32x4){0.f, 0.f, 0.f, 0.f};

    const int gr = lane >> 2, gc8 = (lane & 3) * 8;
    const int ldw = 2 * Kp;
    const int kt0 = SPLITK ? blockIdx.z * ktLen : 0;

    for (int kt = kt0; kt < kt0 + ktLen; kt += 32) {
        if constexpr (BM == 128) {
#pragma unroll
            for (int j = 0; j < 2; ++j) {
                int g = w * 2 + j;
                __builtin_amdgcn_global_load_lds(
                    (const __attribute__((address_space(1))) uint*)(Ap + (size_t)(row0 + g*16 + gr) * lda + kt + gc8),
                    (__attribute__((address_space(3))) uint*)(&As[g * 512]), 16, 0, 0);
            }
        } else {
            int g = w;
            __builtin_amdgcn_global_load_lds(
                (const __attribute__((address_space(1))) uint*)(Ap + (size_t)(row0 + g*16 + gr) * lda + kt + gc8),
                (__attribute__((address_space(3))) uint*)(&As[g * 512]), 16, 0, 0);
        }
#pragma unroll
        for (int j = 0; j < 2; ++j) {
            int g = w * 2 + j;
            const ushort* wsrc = Wp + (size_t)(col0 + g*16 + gr) * ldw + kt + gc8;
            __builtin_amdgcn_global_load_lds(
                (const __attribute__((address_space(1))) uint*)wsrc,
                (__attribute__((address_space(3))) uint*)(&Ws2[g * 512]), 16, 0, 0);
            if constexpr (WLO)
                __builtin_amdgcn_global_load_lds(
                    (const __attribute__((address_space(1))) uint*)(wsrc + Kp),
                    (__attribute__((address_space(3))) uint*)(&Ws2[4096 + g * 512]), 16, 0, 0);
        }
        __syncthreads();

        short8v a[MI], bh[4];
#pragma unroll
        for (int mi = 0; mi < MI; ++mi)
            a[mi] = *reinterpret_cast<const short8v*>(&As[(wr*(BM/2) + mi*16 + lid) * 32 + half * 8]);
#pragma unroll
        for (int ni = 0; ni < 4; ++ni)
            bh[ni] = *reinterpret_cast<const short8v*>(&Ws2[(wc*64 + ni*16 + lid) * 32 + half * 8]);
#pragma unroll
        for (int mi = 0; mi < MI; ++mi)
#pragma unroll
            for (int ni = 0; ni < 4; ++ni)
                acc[mi][ni] = __builtin_amdgcn_mfma_f32_16x16x32_bf16(a[mi], bh[ni], acc[mi][ni], 0, 0, 0);
        if constexpr (WLO) {
            short8v bl[4];
#pragma unroll
            for (int ni = 0; ni < 4; ++ni)
                bl[ni] = *reinterpret_cast<const short8v*>(&Ws2[4096 + (wc*64 + ni*16 + lid) * 32 + half * 8]);
#pragma unroll
            for (int mi = 0; mi < MI; ++mi)
#pragma unroll
                for (int ni = 0; ni < 4; ++ni)
                    acc[mi][ni] = __builtin_amdgcn_mfma_f32_16x16x32_bf16(a[mi], bl[ni], acc[mi][ni], 0, 0, 0);
        }
        __syncthreads();
    }

    if constexpr (SPLITK) {
        float* P = Cf + (size_t)blockIdx.z * M * 128;
#pragma unroll
        for (int mi = 0; mi < MI; ++mi) {
            int r = row0 + wr*(BM/2) + mi*16 + half*4;
#pragma unroll
            for (int ni = 0; ni < 4; ++ni) {
                int c = col0 + wc*64 + ni*16 + lid;
#pragma unroll
                for (int q = 0; q < 4; ++q)
                    P[(size_t)(r + q) * 128 + c] = acc[mi][ni][q];
            }
        }
    } else {
#pragma unroll
        for (int mi = 0; mi < MI; ++mi) {
            int r = row0 + wr*(BM/2) + mi*16 + half*4;
#pragma unroll
            for (int ni = 0; ni < 4; ++ni) {
                int c = col0 + wc*64 + ni*16 + lid;
                if (c >= N) continue;
                float bv = bias ? bias[c] : 0.f;
#pragma unroll
                for (int q = 0; q < 4; ++q) {
                    float v = acc[mi][ni][q] + bv;
                    if constexpr (OUT == 2 || OUT == 4) v = (v > 20.f) ? v : log1pf(__expf(v));
                    if constexpr (OUT == 1 || OUT == 4) Cb[(size_t)(r + q) * ldc + c] = f2bf(v);
                    else                                Cf[(size_t)(r + q) * ldc + c] = v;
                }
            }
        }
    }
}

// ---------------- split-K reduce: f32 out / bf16 mirror / packed B,C ----------------
__global__ __launch_bounds__(256)
void reduce_sk(const float* __restrict__ P, int S, int M,
               const float* __restrict__ bias,
               float* __restrict__ Cf, int ldc, int N,
               ushort* __restrict__ Cb, int nbf, int nbfPad,
               float* __restrict__ Bcp)
{
    int idx = blockIdx.x * 256 + threadIdx.x;
    if (idx >= M * 128) return;
    int c = idx & 127, r = idx >> 7;
    float v = 0.f;
    for (int s = 0; s < S; ++s) v += P[(size_t)s * M * 128 + idx];
    if (bias) v += bias[c];
    if (Cf && c < N) Cf[(size_t)r * ldc + c] = v;
    if (Cb && c < nbfPad) Cb[(size_t)r * nbfPad + c] = (c < nbf) ? f2bf(v) : (ushort)0;
    if (Bcp && c >= Rn && c < Rn + 2 * Nn) Bcp[(size_t)r * 32 + (c - Rn)] = v;
}

// ---------------- depthwise causal conv (K=4) + bias + SiLU, x4 vectorized ----------------
__global__ __launch_bounds__(256)
void conv_silu(const ushort* __restrict__ xz, const float* __restrict__ cw,
               const float* __restrict__ cb, ushort* __restrict__ xo, int rowsTotal)
{
    constexpr int ND4 = DIn / 4;
    int idx = blockIdx.x * 256 + threadIdx.x;
    if (idx >= rowsTotal * ND4) return;
    int d4 = (idx % ND4) * 4, row = idx / ND4, l = row % Ll;
    float4 cbv = *reinterpret_cast<const float4*>(cb + d4);
    float acc[4] = {cbv.x, cbv.y, cbv.z, cbv.w};
    float4 w0 = *reinterpret_cast<const float4*>(cw + (d4 + 0) * 4);
    float4 w1 = *reinterpret_cast<const float4*>(cw + (d4 + 1) * 4);
    float4 w2 = *reinterpret_cast<const float4*>(cw + (d4 + 2) * 4);
    float4 w3 = *reinterpret_cast<const float4*>(cw + (d4 + 3) * 4);
    const float* wv[4] = {(const float*)&w0, (const float*)&w1,
                          (const float*)&w2, (const float*)&w3};
#pragma unroll
    for (int j = 0; j < Kc; ++j) {
        int lo = l - 3 + j;
        if (lo >= 0) {
            ushort4 xv = *reinterpret_cast<const ushort4*>(xz + (size_t)(row - 3 + j) * EOc + d4);
            acc[0] = fmaf(wv[0][j], bf2f(xv.x), acc[0]);
            acc[1] = fmaf(wv[1][j], bf2f(xv.y), acc[1]);
            acc[2] = fmaf(wv[2][j], bf2f(xv.z), acc[2]);
            acc[3] = fmaf(wv[3][j], bf2f(xv.w), acc[3]);
        }
    }
    ushort4 o;
    o.x = f2bf(acc[0] * __builtin_amdgcn_rcpf(1.f + exp2a(-acc[0] * L2E)));
    o.y = f2bf(acc[1] * __builtin_amdgcn_rcpf(1.f + exp2a(-acc[1] * L2E)));
    o.z = f2bf(acc[2] * __builtin_amdgcn_rcpf(1.f + exp2a(-acc[2] * L2E)));
    o.w = f2bf(acc[3] * __builtin_amdgcn_rcpf(1.f + exp2a(-acc[3] * L2E)));
    *reinterpret_cast<ushort4*>(xo + (size_t)row * DIn + d4) = o;
}

// ---------------- selective scan, chunked, NG=2 (8 states / thread) ----------------
// idx = ((b*NCH + c)*DIn + d)*2 + ng; lane pair (2i, 2i+1) shares one d.
// Prefetch reads <=1 row past chunk end: lands inside the next ws buffer (dead value).
__global__ __launch_bounds__(256)
void scan_pass1(const ushort* __restrict__ dtb, const ushort* __restrict__ xab,
                const float* __restrict__ bcp, const float* __restrict__ A_log,
                float* __restrict__ hend, float* __restrict__ Pbuf, int BC)
{
    int idx = blockIdx.x * 256 + threadIdx.x;
    if (idx >= BC * DIn * NCH * 2) return;
    int ng = idx & 1;
    int rest = idx >> 1;
    int d = rest % DIn;
    int t = rest / DIn;
    int c = t % NCH, b = t / NCH;

    float A2[8];
    {
        float4 a0 = *reinterpret_cast<const float4*>(A_log + d * Nn + ng * 8);
        float4 a1 = *reinterpret_cast<const float4*>(A_log + d * Nn + ng * 8 + 4);
        A2[0] = -__expf(a0.x) * L2E; A2[1] = -__expf(a0.y) * L2E;
        A2[2] = -__expf(a0.z) * L2E; A2[3] = -__expf(a0.w) * L2E;
        A2[4] = -__expf(a1.x) * L2E; A2[5] = -__expf(a1.y) * L2E;
        A2[6] = -__expf(a1.z) * L2E; A2[7] = -__expf(a1.w) * L2E;
    }
    float h[8] = {0.f,0.f,0.f,0.f,0.f,0.f,0.f,0.f};
    float S = 0.f;

    const size_t row0 = (size_t)b * Ll + c * CH;
    const ushort* pdt = dtb + row0 * DIn + d;
    const ushort* px  = xab + row0 * DIn + d;
    const float*  pb  = bcp + row0 * 32 + ng * 8;

    float dtv = bf2f(*pdt);
    float xv  = bf2f(*px);
    float4 b0 = *reinterpret_cast<const float4*>(pb);
    float4 b1 = *reinterpret_cast<const float4*>(pb + 4);

    for (int l = 0; l < CH; ++l) {
        pdt += DIn; px += DIn; pb += 32;
        float dtn = bf2f(*pdt);
        float xn  = bf2f(*px);
        float4 bn0 = *reinterpret_cast<const float4*>(pb);
        float4 bn1 = *reinterpret_cast<const float4*>(pb + 4);
        float cx = dtv * xv;
        S += dtv;
        float bb[8] = {b0.x,b0.y,b0.z,b0.w,b1.x,b1.y,b1.z,b1.w};
#pragma unroll
        for (int k = 0; k < 8; ++k) {
            float dA = exp2a(dtv * A2[k]);
            h[k] = fmaf(dA, h[k], cx * bb[k]);
        }
        dtv = dtn; xv = xn; b0 = bn0; b1 = bn1;
    }
    size_t o = (size_t)rest * Nn + ng * 8;
    *reinterpret_cast<float4*>(hend + o)     = (float4){h[0],h[1],h[2],h[3]};
    *reinterpret_cast<float4*>(hend + o + 4) = (float4){h[4],h[5],h[6],h[7]};
    *reinterpret_cast<float4*>(Pbuf + o) =
        (float4){exp2a(A2[0]*S), exp2a(A2[1]*S), exp2a(A2[2]*S), exp2a(A2[3]*S)};
    *reinterpret_cast<float4*>(Pbuf + o + 4) =
        (float4){exp2a(A2[4]*S), exp2a(A2[5]*S), exp2a(A2[6]*S), exp2a(A2[7]*S)};
}

__global__ __launch_bounds__(256)
void scan_pass2(const float* __restrict__ hend, const float* __restrict__ Pbuf,
                float* __restrict__ hstart, int BC)
{
    int idx = blockIdx.x * 256 + threadIdx.x;
    if (idx >= BC * DIn * Nn) return;
    int n = idx % Nn;
    int d = (idx / Nn) % DIn;
    int b = idx / (Nn * DIn);
    float hs = 0.f;
    for (int c = 0; c < NCH; ++c) {
        size_t o = (((size_t)b * NCH + c) * DIn + d) * Nn + n;
        hstart[o] = hs;
        hs = fmaf(Pbuf[o], hs, hend[o]);
    }
}

__global__ __launch_bounds__(256)
void scan_pass3(const ushort* __restrict__ dtb, ushort* __restrict__ xab,
                const float* __restrict__ bcp, const float* __restrict__ A_log,
                const float* __restrict__ Dp, const ushort* __restrict__ xzb,
                const float* __restrict__ hstart, int BC)
{
    int idx = blockIdx.x * 256 + threadIdx.x;
    if (idx >= BC * DIn * NCH * 2) return;
    int ng = idx & 1;
    int rest = idx >> 1;
    int d = rest % DIn;
    int t = rest / DIn;
    int c = t % NCH, b = t / NCH;

    float A2[8];
    {
        float4 a0 = *reinterpret_cast<const float4*>(A_log + d * Nn + ng * 8);
        float4 a1 = *reinterpret_cast<const float4*>(A_log + d * Nn + ng * 8 + 4);
        A2[0] = -__expf(a0.x) * L2E; A2[1] = -__expf(a0.y) * L2E;
        A2[2] = -__expf(a0.z) * L2E; A2[3] = -__expf(a0.w) * L2E;
        A2[4] = -__expf(a1.x) * L2E; A2[5] = -__expf(a1.y) * L2E;
        A2[6] = -__expf(a1.z) * L2E; A2[7] = -__expf(a1.w) * L2E;
    }
    float h[8];
    {
        float4 h0 = *reinterpret_cast<const float4*>(hstart + (size_t)rest * Nn + ng * 8);
        float4 h1 = *reinterpret_cast<const float4*>(hstart + (size_t)rest * Nn + ng * 8 + 4);
        h[0]=h0.x; h[1]=h0.y; h[2]=h0.z; h[3]=h0.w;
        h[4]=h1.x; h[5]=h1.y; h[6]=h1.z; h[7]=h1.w;
    }
    const float Dd = Dp[d];

    const size_t row0 = (size_t)b * Ll + c * CH;
    const ushort* pdt = dtb + row0 * DIn + d;
    ushort*       px  = xab + row0 * DIn + d;
    const ushort* pz  = xzb + row0 * EOc + DIn + d;
    const float*  pb  = bcp + row0 * 32 + ng * 8;
    const float*  pc  = bcp + row0 * 32 + 16 + ng * 8;

    float dtv = bf2f(*pdt);
    float xv  = bf2f(*px);
    float zv  = bf2f(*pz);
    float4 b0 = *reinterpret_cast<const float4*>(pb);
    float4 b1 = *reinterpret_cast<const float4*>(pb + 4);
    float4 c0 = *reinterpret_cast<const float4*>(pc);
    float4 c1 = *reinterpret_cast<const float4*>(pc + 4);

    for (int l = 0; l < CH; ++l) {
        float dtn = bf2f(pdt[DIn]);
        float xn  = bf2f(px[DIn]);
        float zn  = bf2f(pz[EOc]);
        float4 bn0 = *reinterpret_cast<const float4*>(pb + 32);
        float4 bn1 = *reinterpret_cast<const float4*>(pb + 36);
        float4 cn0 = *reinterpret_cast<const float4*>(pc + 32);
        float4 cn1 = *reinterpret_cast<const float4*>(pc + 36);
        float cx = dtv * xv;
        float bb[8] = {b0.x,b0.y,b0.z,b0.w,b1.x,b1.y,b1.z,b1.w};
        float cc[8] = {c0.x,c0.y,c0.z,c0.w,c1.x,c1.y,c1.z,c1.w};
        float y = 0.f;
#pragma unroll
        for (int k = 0; k < 8; ++k) {
            float dA = exp2a(dtv * A2[k]);
            h[k] = fmaf(dA, h[k], cx * bb[k]);
            y = fmaf(h[k], cc[k], y);
        }
        y += __shfl_xor(y, 1);
        y = fmaf(xv, Dd, y);
        float sz = zv * __builtin_amdgcn_rcpf(1.f + exp2a(-zv * L2E));
        if (ng == 0) *px = f2bf(y * sz);
        dtv = dtn; xv = xn; zv = zn; b0 = bn0; b1 = bn1; c0 = cn0; c1 = cn1;
        pdt += DIn; px += DIn; pz += EOc; pb += 32; pc += 32;
    }
}

// ---------------- host launcher ----------------
extern "C" void kernel_launch(void* const* d_in, const int* in_sizes, int n_in,
                              void* d_out, int out_size, void* d_ws, size_t ws_size,
                              hipStream_t stream)
{
    const float* obs        = (const float*)d_in[0];
    const float* w_in       = (const float*)d_in[1];
    const float* b_in       = (const float*)d_in[2];
    const float* in_proj_w  = (const float*)d_in[3];
    const float* conv_w     = (const float*)d_in[4];
    const float* conv_b     = (const float*)d_in[5];
    const float* x_proj_w   = (const float*)d_in[6];
    const float* dt_proj_w  = (const float*)d_in[7];
    const float* dt_proj_b  = (const float*)d_in[8];
    const float* A_log      = (const float*)d_in[9];
    const float* D_skip     = (const float*)d_in[10];
    const float* out_proj_w = (const float*)d_in[11];
    const float* w_out      = (const float*)d_in[12];
    const float* b_out      = (const float*)d_in[13];
    float* out = (float*)d_out;

    auto per_bc = []() -> size_t {
        size_t r = Ll;
        size_t bts = r*EOc*2            // xzb bf16
                   + r*DIn*2            // xab bf16
                   + r*DIn*2            // dtbb bf16
                   + r*32*4             // bcp f32 packed B,C
                   + r*64*2             // dtr
                   + r*DMn*2            // xbuf
                   + r*OBSn*2           // obsb
                   + 3ull*DIn*NCH*Nn*4  // scan aux
                   + 4ull*r*128*4;      // splitK parts
        return bts + 8192;
    };
    const size_t wbytes = WTOT * 2 + 1024;
    int BC = 8;
    while (BC > 1 && wbytes + per_bc() * BC > ws_size) BC >>= 1;

    ushort* WB = (ushort*)d_ws;
    build_wsplit<<<(int)((WQUADS + 255) / 256), 256, 0, stream>>>(
        w_in, in_proj_w, x_proj_w, dt_proj_w, out_proj_w, w_out, WB);

    const size_t WLAY_INP[2] = {WOFF_INP0, WOFF_INP1};
    const size_t WLAY_XP[2]  = {WOFF_XP0,  WOFF_XP1};
    const size_t WLAY_DT[2]  = {WOFF_DT0,  WOFF_DT1};
    const size_t WLAY_OP[2]  = {WOFF_OP0,  WOFF_OP1};

    for (int b0 = 0; b0 < Bb; b0 += BC) {
        const int M = BC * Ll;
        char* base = (char*)d_ws + ((wbytes + 255) & ~(size_t)255);
        auto alloc = [&](size_t bytes) -> char* {
            char* r = base; base += (bytes + 255) & ~(size_t)255; return r;
        };
        ushort* xzb   = (ushort*)alloc((size_t)M * EOc * 2);
        ushort* xab   = (ushort*)alloc((size_t)M * DIn * 2);
        ushort* dtbb  = (ushort*)alloc((size_t)M * DIn * 2);
        float*  bcp   = (float*) alloc((size_t)M * 32 * 4);
        ushort* dtr   = (ushort*)alloc((size_t)M * 64 * 2);
        ushort* xbuf  = (ushort*)alloc((size_t)M * DMn * 2);
        ushort* obsb  = (ushort*)alloc((size_t)M * OBSn * 2);
        const size_t sseg = (size_t)BC * DIn * NCH * Nn;
        float*  hend  = (float*) alloc(sseg * 4);
        float*  Pb    = (float*) alloc(sseg * 4);
        float*  hst   = (float*) alloc(sseg * 4);
        float*  parts = (float*) alloc(4ull * M * 128 * 4);

        build_bf<<<(M * OBSn / 4 + 255) / 256, 256, 0, stream>>>(
            obs + (size_t)b0 * Ll * OBSn, obsb, M * OBSn / 4);
        // in_proj -> bf16 xbuf
        gemm_ws<64, 1, 0><<<dim3(6, M / 64), 256, 0, stream>>>(
            obsb, OBSn, WB + WOFF_WIN, b_in, nullptr, xbuf, DMn, M, DMn, 64, 64);

        for (int layer = 0; layer < NLn; ++layer) {
            const float* cw     = conv_w    + (size_t)layer * DIn * Kc;
            const float* cb     = conv_b    + (size_t)layer * DIn;
            const float* dtbias = dt_proj_b + (size_t)layer * DIn;
            const float* Al     = A_log     + (size_t)layer * DIn * Nn;
            const float* Dpp    = D_skip    + (size_t)layer * DIn;

            // xz -> bf16 [M x 3072]  (hi-only weights: WLO=false)
            gemm_ws<128, 1, 0, false><<<dim3(24, M / 128), 256, 0, stream>>>(
                xbuf, DMn, WB + WLAY_INP[layer], nullptr, nullptr, xzb, EOc, M, EOc, DMn, DMn);
            // conv + SiLU -> bf16 xab
            conv_silu<<<(M * (DIn / 4) + 255) / 256, 256, 0, stream>>>(xzb, cw, cb, xab, M);
            // x_proj: split-K S=4 -> parts -> dtr bf16 (pad 64) + packed B,C f32
            gemm_ws<64, 0, 1><<<dim3(1, M / 64, 4), 256, 0, stream>>>(
                xab, DIn, WB + WLAY_XP[layer], nullptr, parts, nullptr, 128, M, 128, DIn, DIn / 4);
            reduce_sk<<<(M * 128 + 255) / 256, 256, 0, stream>>>(
                parts, 4, M, nullptr, nullptr, 0, 0, dtr, Rn, 64, bcp);
            // dt = softplus(...) -> bf16
            gemm_ws<64, 4, 0><<<dim3(12, M / 64), 256, 0, stream>>>(
                dtr, 64, WB + WLAY_DT[layer], dtbias, nullptr, dtbb, DIn, M, DIn, 64, 64);
            // selective scan
            {
                int tot1 = BC * DIn * NCH * 2;
                scan_pass1<<<(tot1 + 255) / 256, 256, 0, stream>>>(dtbb, xab, bcp, Al, hend, Pb, BC);
                int tot2 = BC * DIn * Nn;
                scan_pass2<<<(tot2 + 255) / 256, 256, 0, stream>>>(hend, Pb, hst, BC);
                scan_pass3<<<(tot1 + 255) / 256, 256, 0, stream>>>(dtbb, xab, bcp, Al, Dpp, xzb, hst, BC);
            }
            // out_proj -> bf16 xbuf
            gemm_ws<64, 1, 0><<<dim3(6, M / 64), 256, 0, stream>>>(
                xab, DIn, WB + WLAY_OP[layer], nullptr, nullptr, xbuf, DMn, M, DMn, DIn, DIn);
        }
        // head: split-K S=4
        gemm_ws<64, 0, 1><<<dim3(1, M / 64, 4), 256, 0, stream>>>(
            xbuf, DMn, WB + WOFF_WOUT, nullptr, parts, nullptr, 128, M, 128, DMn, DMn / 4);
        reduce_sk<<<(M * 128 + 255) / 256, 256, 0, stream>>>(
            parts, 4, M, b_out, out + (size_t)b0 * Ll * ACTn, ACTn, ACTn, nullptr, 0, 0, nullptr);
    }
}

// Round 7
// 1331.458 us; speedup vs baseline: 5.6029x; 1.1081x over previous
//
#include <hip/hip_runtime.h>
#include <cstddef>

// ---------------- problem constants ----------------
constexpr int Bb  = 8;
constexpr int Ll  = 2048;
constexpr int OBSn = 64;
constexpr int ACTn = 16;
constexpr int DMn = 768;
constexpr int DIn = 1536;
constexpr int Nn  = 16;
constexpr int Rn  = 48;
constexpr int Kc  = 4;
constexpr int NLn = 2;
constexpr int XD  = Rn + 2 * Nn;   // 80
constexpr int CH  = 64;            // scan chunk length (smaller -> more waves)
constexpr int NCH = Ll / CH;       // 32
constexpr int EOc = 2 * DIn;       // 3072
constexpr float L2E = 1.4426950408889634f;

typedef __attribute__((ext_vector_type(8))) short short8v;
typedef __attribute__((ext_vector_type(4))) float f32x4;

__device__ inline ushort f2bf(float f) {
    uint u = __float_as_uint(f);
    return (ushort)((u + 0x7FFFu + ((u >> 16) & 1u)) >> 16);   // RNE
}
__device__ inline float bf2f(ushort b) { return __uint_as_float(((uint)b) << 16); }
__device__ inline float exp2a(float x) {            // raw v_exp_f32: D = 2^x
    float r; asm("v_exp_f32 %0, %1" : "=v"(r) : "v"(x)); return r;
}

// ---------------- W' builder: all weights -> [Whi | Wlo] bf16, once ----------------
constexpr size_t WOFF_WIN = 0, WOFF_INP0 = 98304, WOFF_INP1 = 4816896,
                 WOFF_XP0 = 9535488, WOFF_XP1 = 9928704, WOFF_DT0 = 10321920,
                 WOFF_DT1 = 10518528, WOFF_OP0 = 10715136, WOFF_OP1 = 13074432,
                 WOFF_WOUT = 15433728, WTOT = 15630336;   // ushorts
constexpr size_t WQUADS = WTOT / 4;

__global__ __launch_bounds__(256)
void build_wsplit(const float* __restrict__ w_in, const float* __restrict__ inp,
                  const float* __restrict__ xp,  const float* __restrict__ dtp,
                  const float* __restrict__ op,  const float* __restrict__ wout,
                  ushort* __restrict__ WB)
{
    constexpr int NS = 10;
    constexpr int    sSel[NS] = {0,1,1,2,2,3,3,4,4,5};
    constexpr size_t sOff[NS] = {0, 0, 3072ull*768, 0, 80ull*1536, 0, 1536ull*48, 0, 768ull*1536, 0};
    constexpr int    sN[NS]   = {768,3072,3072,80,80,1536,1536,768,768,16};
    constexpr int    sK[NS]   = {64,768,768,1536,1536,48,48,1536,1536,768};
    constexpr int    sKp[NS]  = {64,768,768,1536,1536,64,64,1536,1536,768};
    constexpr size_t sD[NS]   = {WOFF_WIN,WOFF_INP0,WOFF_INP1,WOFF_XP0,WOFF_XP1,
                                 WOFF_DT0,WOFF_DT1,WOFF_OP0,WOFF_OP1,WOFF_WOUT};
    constexpr size_t sQ[NS+1] = {0,24576,1204224,2383872,2482176,2580480,
                                 2629632,2678784,3268608,3858432,3907584};

    size_t qid = (size_t)blockIdx.x * 256 + threadIdx.x;
    if (qid >= sQ[NS]) return;
    int s = 0;
#pragma unroll
    for (int i = 0; i < NS; ++i) if (qid >= sQ[i+1]) s = i + 1;

    size_t local = qid - sQ[s];
    const int Kp = sKp[s], K = sK[s], N = sN[s];
    const int ncol4 = (2 * Kp) >> 2;
    const int n  = (int)(local / ncol4);
    const int c4 = (int)(local % ncol4) * 4;
    const bool lo = (c4 >= Kp);
    const int sc = lo ? c4 - Kp : c4;
    ushort4 o; o.x = o.y = o.z = o.w = 0;
    if (n < N && sc < K) {
        const float* src;
        switch (sSel[s]) { case 0: src = w_in; break; case 1: src = inp; break;
                           case 2: src = xp;   break; case 3: src = dtp; break;
                           case 4: src = op;   break; default: src = wout; }
        float4 v = *reinterpret_cast<const float4*>(src + sOff[s] + (size_t)n * K + sc);
        ushort h0 = f2bf(v.x), h1 = f2bf(v.y), h2 = f2bf(v.z), h3 = f2bf(v.w);
        if (lo) {
            h0 = f2bf(v.x - bf2f(h0)); h1 = f2bf(v.y - bf2f(h1));
            h2 = f2bf(v.z - bf2f(h2)); h3 = f2bf(v.w - bf2f(h3));
        }
        o.x = h0; o.y = h1; o.z = h2; o.w = h3;
    }
    *reinterpret_cast<ushort4*>(WB + sD[s] + (size_t)n * (2 * Kp) + c4) = o;
}

__global__ __launch_bounds__(256)
void build_bf(const float* __restrict__ src, ushort* __restrict__ dst, int n4)
{
    int i = blockIdx.x * 256 + threadIdx.x;
    if (i >= n4) return;
    float4 v = *reinterpret_cast<const float4*>(src + (size_t)i * 4);
    ushort4 o; o.x = f2bf(v.x); o.y = f2bf(v.y); o.z = f2bf(v.z); o.w = f2bf(v.w);
    *reinterpret_cast<ushort4*>(dst + (size_t)i * 4) = o;
}

// ---------------- MFMA GEMM (A bf16 [MxKp], W' [Npad x 2Kp]) ----------------
// OUT: 0=f32, 1=bf16, 2=softplus f32, 4=softplus bf16. SPLITK: raw partials.
// WLO=false: use only the hi half of W' (single-bf16 weights).
template<int BM, int OUT, int SPLITK, bool WLO = true>
__global__ __launch_bounds__(256)
void gemm_ws(const ushort* __restrict__ Ap, int lda,
             const ushort* __restrict__ Wp,
             const float* __restrict__ bias,
             float* __restrict__ Cf, ushort* __restrict__ Cb, int ldc,
             int M, int N, int Kp, int ktLen)
{
    constexpr int MI = BM / 32;
    __shared__ ushort As[BM * 32];
    __shared__ ushort Ws2[WLO ? 8192 : 4096];

    const int nwgx = gridDim.x;
    const int nwg  = nwgx * gridDim.y;
    int bid = blockIdx.y * nwgx + blockIdx.x;
    {   // bijective XCD swizzle
        int q = nwg >> 3, r = nwg & 7;
        int x = bid & 7, lc = bid >> 3;
        bid = (x < r ? x * (q + 1) : r * (q + 1) + (x - r) * q) + lc;
    }
    const int col0 = (bid % nwgx) * 128;
    const int row0 = (bid / nwgx) * BM;

    const int tid = threadIdx.x, w = tid >> 6, lane = tid & 63;
    const int wr = w >> 1, wc = w & 1, half = lane >> 4, lid = lane & 15;

    f32x4 acc[MI][4];
#pragma unroll
    for (int i = 0; i < MI; ++i)
#pragma unroll
        for (int j = 0; j < 4; ++j) acc[i][j] = (f32x4){0.f, 0.f, 0.f, 0.f};

    const int gr = lane >> 2, gc8 = (lane & 3) * 8;
    const int ldw = 2 * Kp;
    const int kt0 = SPLITK ? blockIdx.z * ktLen : 0;

    for (int kt = kt0; kt < kt0 + ktLen; kt += 32) {
        if constexpr (BM == 128) {
#pragma unroll
            for (int j = 0; j < 2; ++j) {
                int g = w * 2 + j;
                __builtin_amdgcn_global_load_lds(
                    (const __attribute__((address_space(1))) uint*)(Ap + (size_t)(row0 + g*16 + gr) * lda + kt + gc8),
                    (__attribute__((address_space(3))) uint*)(&As[g * 512]), 16, 0, 0);
            }
        } else {
            int g = w;
            __builtin_amdgcn_global_load_lds(
                (const __attribute__((address_space(1))) uint*)(Ap + (size_t)(row0 + g*16 + gr) * lda + kt + gc8),
                (__attribute__((address_space(3))) uint*)(&As[g * 512]), 16, 0, 0);
        }
#pragma unroll
        for (int j = 0; j < 2; ++j) {
            int g = w * 2 + j;
            const ushort* wsrc = Wp + (size_t)(col0 + g*16 + gr) * ldw + kt + gc8;
            __builtin_amdgcn_global_load_lds(
                (const __attribute__((address_space(1))) uint*)wsrc,
                (__attribute__((address_space(3))) uint*)(&Ws2[g * 512]), 16, 0, 0);
            if constexpr (WLO)
                __builtin_amdgcn_global_load_lds(
                    (const __attribute__((address_space(1))) uint*)(wsrc + Kp),
                    (__attribute__((address_space(3))) uint*)(&Ws2[4096 + g * 512]), 16, 0, 0);
        }
        __syncthreads();

        short8v a[MI], bh[4];
#pragma unroll
        for (int mi = 0; mi < MI; ++mi)
            a[mi] = *reinterpret_cast<const short8v*>(&As[(wr*(BM/2) + mi*16 + lid) * 32 + half * 8]);
#pragma unroll
        for (int ni = 0; ni < 4; ++ni)
            bh[ni] = *reinterpret_cast<const short8v*>(&Ws2[(wc*64 + ni*16 + lid) * 32 + half * 8]);
#pragma unroll
        for (int mi = 0; mi < MI; ++mi)
#pragma unroll
            for (int ni = 0; ni < 4; ++ni)
                acc[mi][ni] = __builtin_amdgcn_mfma_f32_16x16x32_bf16(a[mi], bh[ni], acc[mi][ni], 0, 0, 0);
        if constexpr (WLO) {
            short8v bl[4];
#pragma unroll
            for (int ni = 0; ni < 4; ++ni)
                bl[ni] = *reinterpret_cast<const short8v*>(&Ws2[4096 + (wc*64 + ni*16 + lid) * 32 + half * 8]);
#pragma unroll
            for (int mi = 0; mi < MI; ++mi)
#pragma unroll
                for (int ni = 0; ni < 4; ++ni)
                    acc[mi][ni] = __builtin_amdgcn_mfma_f32_16x16x32_bf16(a[mi], bl[ni], acc[mi][ni], 0, 0, 0);
        }
        __syncthreads();
    }

    if constexpr (SPLITK) {
        float* P = Cf + (size_t)blockIdx.z * M * 128;
#pragma unroll
        for (int mi = 0; mi < MI; ++mi) {
            int r = row0 + wr*(BM/2) + mi*16 + half*4;
#pragma unroll
            for (int ni = 0; ni < 4; ++ni) {
                int c = col0 + wc*64 + ni*16 + lid;
#pragma unroll
                for (int q = 0; q < 4; ++q)
                    P[(size_t)(r + q) * 128 + c] = acc[mi][ni][q];
            }
        }
    } else {
#pragma unroll
        for (int mi = 0; mi < MI; ++mi) {
            int r = row0 + wr*(BM/2) + mi*16 + half*4;
#pragma unroll
            for (int ni = 0; ni < 4; ++ni) {
                int c = col0 + wc*64 + ni*16 + lid;
                if (c >= N) continue;
                float bv = bias ? bias[c] : 0.f;
#pragma unroll
                for (int q = 0; q < 4; ++q) {
                    float v = acc[mi][ni][q] + bv;
                    if constexpr (OUT == 2 || OUT == 4) v = (v > 20.f) ? v : log1pf(__expf(v));
                    if constexpr (OUT == 1 || OUT == 4) Cb[(size_t)(r + q) * ldc + c] = f2bf(v);
                    else                                Cf[(size_t)(r + q) * ldc + c] = v;
                }
            }
        }
    }
}

// ---------------- split-K reduce: f32 out / bf16 mirror / packed B,C ----------------
__global__ __launch_bounds__(256)
void reduce_sk(const float* __restrict__ P, int S, int M,
               const float* __restrict__ bias,
               float* __restrict__ Cf, int ldc, int N,
               ushort* __restrict__ Cb, int nbf, int nbfPad,
               float* __restrict__ Bcp)
{
    int idx = blockIdx.x * 256 + threadIdx.x;
    if (idx >= M * 128) return;
    int c = idx & 127, r = idx >> 7;
    float v = 0.f;
    for (int s = 0; s < S; ++s) v += P[(size_t)s * M * 128 + idx];
    if (bias) v += bias[c];
    if (Cf && c < N) Cf[(size_t)r * ldc + c] = v;
    if (Cb && c < nbfPad) Cb[(size_t)r * nbfPad + c] = (c < nbf) ? f2bf(v) : (ushort)0;
    if (Bcp && c >= Rn && c < Rn + 2 * Nn) Bcp[(size_t)r * 32 + (c - Rn)] = v;
}

// ---------------- depthwise causal conv (K=4) + bias + SiLU, x4 vectorized ----------------
__global__ __launch_bounds__(256)
void conv_silu(const ushort* __restrict__ xz, const float* __restrict__ cw,
               const float* __restrict__ cb, ushort* __restrict__ xo, int rowsTotal)
{
    constexpr int ND4 = DIn / 4;
    int idx = blockIdx.x * 256 + threadIdx.x;
    if (idx >= rowsTotal * ND4) return;
    int d4 = (idx % ND4) * 4, row = idx / ND4, l = row % Ll;
    float4 cbv = *reinterpret_cast<const float4*>(cb + d4);
    float acc[4] = {cbv.x, cbv.y, cbv.z, cbv.w};
    float4 w0 = *reinterpret_cast<const float4*>(cw + (d4 + 0) * 4);
    float4 w1 = *reinterpret_cast<const float4*>(cw + (d4 + 1) * 4);
    float4 w2 = *reinterpret_cast<const float4*>(cw + (d4 + 2) * 4);
    float4 w3 = *reinterpret_cast<const float4*>(cw + (d4 + 3) * 4);
    const float* wv[4] = {(const float*)&w0, (const float*)&w1,
                          (const float*)&w2, (const float*)&w3};
#pragma unroll
    for (int j = 0; j < Kc; ++j) {
        int lo = l - 3 + j;
        if (lo >= 0) {
            ushort4 xv = *reinterpret_cast<const ushort4*>(xz + (size_t)(row - 3 + j) * EOc + d4);
            acc[0] = fmaf(wv[0][j], bf2f(xv.x), acc[0]);
            acc[1] = fmaf(wv[1][j], bf2f(xv.y), acc[1]);
            acc[2] = fmaf(wv[2][j], bf2f(xv.z), acc[2]);
            acc[3] = fmaf(wv[3][j], bf2f(xv.w), acc[3]);
        }
    }
    ushort4 o;
    o.x = f2bf(acc[0] * __builtin_amdgcn_rcpf(1.f + exp2a(-acc[0] * L2E)));
    o.y = f2bf(acc[1] * __builtin_amdgcn_rcpf(1.f + exp2a(-acc[1] * L2E)));
    o.z = f2bf(acc[2] * __builtin_amdgcn_rcpf(1.f + exp2a(-acc[2] * L2E)));
    o.w = f2bf(acc[3] * __builtin_amdgcn_rcpf(1.f + exp2a(-acc[3] * L2E)));
    *reinterpret_cast<ushort4*>(xo + (size_t)row * DIn + d4) = o;
}

// ---------------- selective scan, chunked, NG=2 (8 states / thread) ----------------
// idx = ((b*NCH + c)*DIn + d)*2 + ng; lane pair (2i, 2i+1) shares one d.
// Prefetch reads <=1 row past chunk end: lands inside the next ws buffer (dead value).
__global__ __launch_bounds__(256)
void scan_pass1(const ushort* __restrict__ dtb, const ushort* __restrict__ xab,
                const float* __restrict__ bcp, const float* __restrict__ A_log,
                float* __restrict__ hend, float* __restrict__ Pbuf, int BC)
{
    int idx = blockIdx.x * 256 + threadIdx.x;
    if (idx >= BC * DIn * NCH * 2) return;
    int ng = idx & 1;
    int rest = idx >> 1;
    int d = rest % DIn;
    int t = rest / DIn;
    int c = t % NCH, b = t / NCH;

    float A2[8];
    {
        float4 a0 = *reinterpret_cast<const float4*>(A_log + d * Nn + ng * 8);
        float4 a1 = *reinterpret_cast<const float4*>(A_log + d * Nn + ng * 8 + 4);
        A2[0] = -__expf(a0.x) * L2E; A2[1] = -__expf(a0.y) * L2E;
        A2[2] = -__expf(a0.z) * L2E; A2[3] = -__expf(a0.w) * L2E;
        A2[4] = -__expf(a1.x) * L2E; A2[5] = -__expf(a1.y) * L2E;
        A2[6] = -__expf(a1.z) * L2E; A2[7] = -__expf(a1.w) * L2E;
    }
    float h[8] = {0.f,0.f,0.f,0.f,0.f,0.f,0.f,0.f};
    float S = 0.f;

    const size_t row0 = (size_t)b * Ll + c * CH;
    const ushort* pdt = dtb + row0 * DIn + d;
    const ushort* px  = xab + row0 * DIn + d;
    const float*  pb  = bcp + row0 * 32 + ng * 8;

    float dtv = bf2f(*pdt);
    float xv  = bf2f(*px);
    float4 b0 = *reinterpret_cast<const float4*>(pb);
    float4 b1 = *reinterpret_cast<const float4*>(pb + 4);

    for (int l = 0; l < CH; ++l) {
        pdt += DIn; px += DIn; pb += 32;
        float dtn = bf2f(*pdt);
        float xn  = bf2f(*px);
        float4 bn0 = *reinterpret_cast<const float4*>(pb);
        float4 bn1 = *reinterpret_cast<const float4*>(pb + 4);
        float cx = dtv * xv;
        S += dtv;
        float bb[8] = {b0.x,b0.y,b0.z,b0.w,b1.x,b1.y,b1.z,b1.w};
#pragma unroll
        for (int k = 0; k < 8; ++k) {
            float dA = exp2a(dtv * A2[k]);
            h[k] = fmaf(dA, h[k], cx * bb[k]);
        }
        dtv = dtn; xv = xn; b0 = bn0; b1 = bn1;
    }
    size_t o = (size_t)rest * Nn + ng * 8;
    *reinterpret_cast<float4*>(hend + o)     = (float4){h[0],h[1],h[2],h[3]};
    *reinterpret_cast<float4*>(hend + o + 4) = (float4){h[4],h[5],h[6],h[7]};
    *reinterpret_cast<float4*>(Pbuf + o) =
        (float4){exp2a(A2[0]*S), exp2a(A2[1]*S), exp2a(A2[2]*S), exp2a(A2[3]*S)};
    *reinterpret_cast<float4*>(Pbuf + o + 4) =
        (float4){exp2a(A2[4]*S), exp2a(A2[5]*S), exp2a(A2[6]*S), exp2a(A2[7]*S)};
}

__global__ __launch_bounds__(256)
void scan_pass2(const float* __restrict__ hend, const float* __restrict__ Pbuf,
                float* __restrict__ hstart, int BC)
{
    int idx = blockIdx.x * 256 + threadIdx.x;
    if (idx >= BC * DIn * Nn) return;
    int n = idx % Nn;
    int d = (idx / Nn) % DIn;
    int b = idx / (Nn * DIn);
    float hs = 0.f;
    for (int c = 0; c < NCH; ++c) {
        size_t o = (((size_t)b * NCH + c) * DIn + d) * Nn + n;
        hstart[o] = hs;
        hs = fmaf(Pbuf[o], hs, hend[o]);
    }
}

__global__ __launch_bounds__(256)
void scan_pass3(const ushort* __restrict__ dtb, ushort* __restrict__ xab,
                const float* __restrict__ bcp, const float* __restrict__ A_log,
                const float* __restrict__ Dp, const ushort* __restrict__ xzb,
                const float* __restrict__ hstart, int BC)
{
    int idx = blockIdx.x * 256 + threadIdx.x;
    if (idx >= BC * DIn * NCH * 2) return;
    int ng = idx & 1;
    int rest = idx >> 1;
    int d = rest % DIn;
    int t = rest / DIn;
    int c = t % NCH, b = t / NCH;

    float A2[8];
    {
        float4 a0 = *reinterpret_cast<const float4*>(A_log + d * Nn + ng * 8);
        float4 a1 = *reinterpret_cast<const float4*>(A_log + d * Nn + ng * 8 + 4);
        A2[0] = -__expf(a0.x) * L2E; A2[1] = -__expf(a0.y) * L2E;
        A2[2] = -__expf(a0.z) * L2E; A2[3] = -__expf(a0.w) * L2E;
        A2[4] = -__expf(a1.x) * L2E; A2[5] = -__expf(a1.y) * L2E;
        A2[6] = -__expf(a1.z) * L2E; A2[7] = -__expf(a1.w) * L2E;
    }
    float h[8];
    {
        float4 h0 = *reinterpret_cast<const float4*>(hstart + (size_t)rest * Nn + ng * 8);
        float4 h1 = *reinterpret_cast<const float4*>(hstart + (size_t)rest * Nn + ng * 8 + 4);
        h[0]=h0.x; h[1]=h0.y; h[2]=h0.z; h[3]=h0.w;
        h[4]=h1.x; h[5]=h1.y; h[6]=h1.z; h[7]=h1.w;
    }
    const float Dd = Dp[d];

    const size_t row0 = (size_t)b * Ll + c * CH;
    const ushort* pdt = dtb + row0 * DIn + d;
    ushort*       px  = xab + row0 * DIn + d;
    const ushort* pz  = xzb + row0 * EOc + DIn + d;
    const float*  pb  = bcp + row0 * 32 + ng * 8;
    const float*  pc  = bcp + row0 * 32 + 16 + ng * 8;

    float dtv = bf2f(*pdt);
    float xv  = bf2f(*px);
    float zv  = bf2f(*pz);
    float4 b0 = *reinterpret_cast<const float4*>(pb);
    float4 b1 = *reinterpret_cast<const float4*>(pb + 4);
    float4 c0 = *reinterpret_cast<const float4*>(pc);
    float4 c1 = *reinterpret_cast<const float4*>(pc + 4);

    for (int l = 0; l < CH; ++l) {
        float dtn = bf2f(pdt[DIn]);
        float xn  = bf2f(px[DIn]);
        float zn  = bf2f(pz[EOc]);
        float4 bn0 = *reinterpret_cast<const float4*>(pb + 32);
        float4 bn1 = *reinterpret_cast<const float4*>(pb + 36);
        float4 cn0 = *reinterpret_cast<const float4*>(pc + 32);
        float4 cn1 = *reinterpret_cast<const float4*>(pc + 36);
        float cx = dtv * xv;
        float bb[8] = {b0.x,b0.y,b0.z,b0.w,b1.x,b1.y,b1.z,b1.w};
        float cc[8] = {c0.x,c0.y,c0.z,c0.w,c1.x,c1.y,c1.z,c1.w};
        float y = 0.f;
#pragma unroll
        for (int k = 0; k < 8; ++k) {
            float dA = exp2a(dtv * A2[k]);
            h[k] = fmaf(dA, h[k], cx * bb[k]);
            y = fmaf(h[k], cc[k], y);
        }
        y += __shfl_xor(y, 1);
        y = fmaf(xv, Dd, y);
        float sz = zv * __builtin_amdgcn_rcpf(1.f + exp2a(-zv * L2E));
        if (ng == 0) *px = f2bf(y * sz);
        dtv = dtn; xv = xn; zv = zn; b0 = bn0; b1 = bn1; c0 = cn0; c1 = cn1;
        pdt += DIn; px += DIn; pz += EOc; pb += 32; pc += 32;
    }
}

// ---------------- host launcher ----------------
extern "C" void kernel_launch(void* const* d_in, const int* in_sizes, int n_in,
                              void* d_out, int out_size, void* d_ws, size_t ws_size,
                              hipStream_t stream)
{
    const float* obs        = (const float*)d_in[0];
    const float* w_in       = (const float*)d_in[1];
    const float* b_in       = (const float*)d_in[2];
    const float* in_proj_w  = (const float*)d_in[3];
    const float* conv_w     = (const float*)d_in[4];
    const float* conv_b     = (const float*)d_in[5];
    const float* x_proj_w   = (const float*)d_in[6];
    const float* dt_proj_w  = (const float*)d_in[7];
    const float* dt_proj_b  = (const float*)d_in[8];
    const float* A_log      = (const float*)d_in[9];
    const float* D_skip     = (const float*)d_in[10];
    const float* out_proj_w = (const float*)d_in[11];
    const float* w_out      = (const float*)d_in[12];
    const float* b_out      = (const float*)d_in[13];
    float* out = (float*)d_out;

    // scan aux (3 arrays) and split-K parts have disjoint lifetimes -> shared region
    auto aux_bc   = []() -> size_t { return 3ull * DIn * NCH * Nn * 4; };       // per batch elem
    auto parts_bc = []() -> size_t { return 4ull * Ll * 128 * 4; };
    auto per_bc = [&]() -> size_t {
        size_t r = Ll;
        size_t bts = r*EOc*2            // xzb bf16
                   + r*DIn*2            // xab bf16
                   + r*DIn*2            // dtbb bf16
                   + r*32*4             // bcp f32 packed B,C
                   + r*64*2             // dtr
                   + r*DMn*2            // xbuf
                   + r*OBSn*2;          // obsb
        size_t shared = aux_bc() > parts_bc() ? aux_bc() : parts_bc();
        return bts + shared + 8192;
    };
    const size_t wbytes = WTOT * 2 + 1024;
    int BC = 8;
    while (BC > 1 && wbytes + per_bc() * BC > ws_size) BC >>= 1;

    ushort* WB = (ushort*)d_ws;
    build_wsplit<<<(int)((WQUADS + 255) / 256), 256, 0, stream>>>(
        w_in, in_proj_w, x_proj_w, dt_proj_w, out_proj_w, w_out, WB);

    const size_t WLAY_INP[2] = {WOFF_INP0, WOFF_INP1};
    const size_t WLAY_XP[2]  = {WOFF_XP0,  WOFF_XP1};
    const size_t WLAY_DT[2]  = {WOFF_DT0,  WOFF_DT1};
    const size_t WLAY_OP[2]  = {WOFF_OP0,  WOFF_OP1};

    for (int b0 = 0; b0 < Bb; b0 += BC) {
        const int M = BC * Ll;
        char* base = (char*)d_ws + ((wbytes + 255) & ~(size_t)255);
        auto alloc = [&](size_t bytes) -> char* {
            char* r = base; base += (bytes + 255) & ~(size_t)255; return r;
        };
        ushort* xzb   = (ushort*)alloc((size_t)M * EOc * 2);
        ushort* xab   = (ushort*)alloc((size_t)M * DIn * 2);
        ushort* dtbb  = (ushort*)alloc((size_t)M * DIn * 2);
        float*  bcp   = (float*) alloc((size_t)M * 32 * 4);
        ushort* dtr   = (ushort*)alloc((size_t)M * 64 * 2);
        ushort* xbuf  = (ushort*)alloc((size_t)M * DMn * 2);
        ushort* obsb  = (ushort*)alloc((size_t)M * OBSn * 2);
        // shared region: split-K parts  OR  scan aux (hend/Pb/hst)
        const size_t sseg = (size_t)BC * DIn * NCH * Nn;          // floats per array
        size_t shared_bytes = 3 * sseg * 4;
        if ((size_t)BC * parts_bc() > shared_bytes) shared_bytes = (size_t)BC * parts_bc();
        char* shared = alloc(shared_bytes);
        float* parts = (float*)shared;
        float* hend  = (float*)shared;
        float* Pb    = (float*)(shared + sseg * 4);
        float* hst   = (float*)(shared + 2 * sseg * 4);

        build_bf<<<(M * OBSn / 4 + 255) / 256, 256, 0, stream>>>(
            obs + (size_t)b0 * Ll * OBSn, obsb, M * OBSn / 4);
        // in_proj -> bf16 xbuf
        gemm_ws<64, 1, 0><<<dim3(6, M / 64), 256, 0, stream>>>(
            obsb, OBSn, WB + WOFF_WIN, b_in, nullptr, xbuf, DMn, M, DMn, 64, 64);

        for (int layer = 0; layer < NLn; ++layer) {
            const float* cw     = conv_w    + (size_t)layer * DIn * Kc;
            const float* cb     = conv_b    + (size_t)layer * DIn;
            const float* dtbias = dt_proj_b + (size_t)layer * DIn;
            const float* Al     = A_log     + (size_t)layer * DIn * Nn;
            const float* Dpp    = D_skip    + (size_t)layer * DIn;

            // xz -> bf16 [M x 3072]  (hi-only weights)
            gemm_ws<128, 1, 0, false><<<dim3(24, M / 128), 256, 0, stream>>>(
                xbuf, DMn, WB + WLAY_INP[layer], nullptr, nullptr, xzb, EOc, M, EOc, DMn, DMn);
            // conv + SiLU -> bf16 xab
            conv_silu<<<(M * (DIn / 4) + 255) / 256, 256, 0, stream>>>(xzb, cw, cb, xab, M);
            // x_proj: split-K S=4 -> parts -> dtr bf16 (pad 64) + packed B,C f32
            gemm_ws<64, 0, 1><<<dim3(1, M / 64, 4), 256, 0, stream>>>(
                xab, DIn, WB + WLAY_XP[layer], nullptr, parts, nullptr, 128, M, 128, DIn, DIn / 4);
            reduce_sk<<<(M * 128 + 255) / 256, 256, 0, stream>>>(
                parts, 4, M, nullptr, nullptr, 0, 0, dtr, Rn, 64, bcp);
            // dt = softplus(...) -> bf16
            gemm_ws<64, 4, 0><<<dim3(12, M / 64), 256, 0, stream>>>(
                dtr, 64, WB + WLAY_DT[layer], dtbias, nullptr, dtbb, DIn, M, DIn, 64, 64);
            // selective scan (aux region reuses parts' memory — disjoint lifetime)
            {
                int tot1 = BC * DIn * NCH * 2;
                scan_pass1<<<(tot1 + 255) / 256, 256, 0, stream>>>(dtbb, xab, bcp, Al, hend, Pb, BC);
                int tot2 = BC * DIn * Nn;
                scan_pass2<<<(tot2 + 255) / 256, 256, 0, stream>>>(hend, Pb, hst, BC);
                scan_pass3<<<(tot1 + 255) / 256, 256, 0, stream>>>(dtbb, xab, bcp, Al, Dpp, xzb, hst, BC);
            }
            // out_proj -> bf16 xbuf  (hi-only weights)
            gemm_ws<64, 1, 0, false><<<dim3(6, M / 64), 256, 0, stream>>>(
                xab, DIn, WB + WLAY_OP[layer], nullptr, nullptr, xbuf, DMn, M, DMn, DIn, DIn);
        }
        // head: split-K S=4
        gemm_ws<64, 0, 1><<<dim3(1, M / 64, 4), 256, 0, stream>>>(
            xbuf, DMn, WB + WOFF_WOUT, nullptr, parts, nullptr, 128, M, 128, DMn, DMn / 4);
        reduce_sk<<<(M * 128 + 255) / 256, 256, 0, stream>>>(
            parts, 4, M, b_out, out + (size_t)b0 * Ll * ACTn, ACTn, ACTn, nullptr, 0, 0, nullptr);
    }
}